// Round 11
// baseline (2035.797 us; speedup 1.0000x reference)
//
#include <hip/hip_runtime.h>
#include <stdint.h>

// ---------------------------------------------------------------------------
// PerceiverResampler on MI355X (gfx950)
// B=32, F=2048, DIM=1024, INNER=1024, H=16, DH=64, Q=64, DEPTH=6, MULT=2
//
// Round 11: (1) KV projections merged 2-depths-per-dispatch (N=4096, 3
// dispatches, KVBUF 512MB) - same math, fewer tails, 2x A-panel reuse.
// (2) Flash-split attention: 2 key-chunks per (b,h) -> 1024 blocks, partial
// (m,l,O) in f32 scratch + combine kernel (exact max-rebase merge).
// ---------------------------------------------------------------------------

#define DEV static __device__ __forceinline__

typedef __attribute__((ext_vector_type(8))) short short8;
typedef __attribute__((ext_vector_type(4))) float f32x4;
typedef __attribute__((ext_vector_type(4))) int int4v;
typedef __attribute__((ext_vector_type(4))) unsigned short ushort4v;
typedef unsigned short ushort_t;

DEV float bf2f(ushort_t u){ union{uint32_t i; float f;} x; x.i = ((uint32_t)u)<<16; return x.f; }
DEV ushort_t f2bf(float f){
  union{float f; uint32_t i;} x; x.f = f;
  uint32_t r = x.i + 0x7fffu + ((x.i>>16)&1u);  // RNE
  return (ushort_t)(r>>16);
}

#define GLOAD16(gp, lp) __builtin_amdgcn_global_load_lds( \
    (const __attribute__((address_space(1))) uint32_t*)(gp), \
    (__attribute__((address_space(3))) uint32_t*)(lp), 16, 0, 0)

#define VMCNT(n) asm volatile("s_waitcnt vmcnt(" #n ")" ::: "memory")
#define CFENCE   asm volatile("" ::: "memory")
#define MFMA16(a,b,c) __builtin_amdgcn_mfma_f32_16x16x32_bf16(a,b,c,0,0,0)
#define MFMAI8(a,b,c) __builtin_amdgcn_mfma_i32_16x16x64_i8(a,b,c,0,0,0)

template<int NXB>
DEV void xcd_remapN(int g, int total, int& x, int& y){
  int xcd = g & 7;
  int k = g >> 3;
  int rows_per_xcd = (total / NXB) >> 3;
  y = xcd * rows_per_xcd + (k / NXB);
  x = k % NXB;
}

DEV void wreduce2(float& a, float& b){
  #pragma unroll
  for (int d = 32; d; d >>= 1){ a += __shfl_xor(a, d); b += __shfl_xor(b, d); }
}

// ---------------- mask compaction ------------------------------------------
__global__ __launch_bounds__(256) void k_compact(const int* __restrict__ mask,
                                                 int* __restrict__ idx, int* __restrict__ cnt){
  int b = blockIdx.x, t = threadIdx.x;
  const int* mb = mask + b*2048;
  int keep[8]; int c = 0;
  #pragma unroll
  for (int u = 0; u < 8; ++u){ keep[u] = (mb[t*8+u] != 0); c += keep[u]; }
  __shared__ int s[256];
  s[t] = c; __syncthreads();
  for (int off = 1; off < 256; off <<= 1){
    int v = (t >= off) ? s[t-off] : 0;
    __syncthreads();
    s[t] += v;
    __syncthreads();
  }
  int pos = s[t] - c;
  #pragma unroll
  for (int u = 0; u < 8; ++u) if (keep[u]) idx[b*2048 + pos++] = t*8 + u;
  if (t == 255) cnt[b] = s[255];
}

// ---------------- gather + rownorm features -> bf16 (wave-per-row) ---------
__global__ __launch_bounds__(256) void k_gather_norm(const float* __restrict__ feat,
        const int* __restrict__ idx, const int* __restrict__ cnt, ushort_t* __restrict__ outp){
  int w = threadIdx.x >> 6, l = threadIdx.x & 63;
  int row = blockIdx.x*4 + w;
  int b = row >> 11, j = row & 2047;
  if (j >= cnt[b]) return;
  int src = idx[b*2048 + j];
  const float* rp = feat + ((size_t)(b*2048 + src))*1024;
  float4 v[4]; float s = 0.f, q = 0.f;
  #pragma unroll
  for (int i = 0; i < 4; ++i){
    v[i] = *(const float4*)(rp + i*256 + l*4);
    s += v[i].x+v[i].y+v[i].z+v[i].w;
    q += v[i].x*v[i].x+v[i].y*v[i].y+v[i].z*v[i].z+v[i].w*v[i].w;
  }
  wreduce2(s, q);
  float mean = s * (1.f/1024.f);
  float rstd = rsqrtf(q*(1.f/1024.f) - mean*mean + 1e-5f);
  ushort_t* op = outp + (size_t)row*1024;
  #pragma unroll
  for (int i = 0; i < 4; ++i){
    ushort4v o;
    o.x = f2bf((v[i].x-mean)*rstd); o.y = f2bf((v[i].y-mean)*rstd);
    o.z = f2bf((v[i].z-mean)*rstd); o.w = f2bf((v[i].w-mean)*rstd);
    *(ushort4v*)(op + i*256 + l*4) = o;
  }
}

// ---------------- rownorm bf16 -> i8 + per-row scale (cnt nullable) --------
__global__ __launch_bounds__(256) void k_rownorm_i8(const ushort_t* __restrict__ in,
        int8_t* __restrict__ outp, float* __restrict__ sca, const int* __restrict__ cnt){
  int w = threadIdx.x >> 6, l = threadIdx.x & 63;
  int row = blockIdx.x*4 + w;
  if (cnt){ int b = row >> 11; if ((row & 2047) >= cnt[b]) return; }
  const ushort_t* rp = in + (size_t)row*1024 + l*16;
  float f[16]; float s = 0.f, q = 0.f;
  #pragma unroll
  for (int i = 0; i < 4; ++i){
    ushort4v u = *(const ushort4v*)(rp + i*4);
    f[i*4+0] = bf2f(u.x); f[i*4+1] = bf2f(u.y);
    f[i*4+2] = bf2f(u.z); f[i*4+3] = bf2f(u.w);
  }
  #pragma unroll
  for (int jj = 0; jj < 16; ++jj){ s += f[jj]; q += f[jj]*f[jj]; }
  wreduce2(s, q);
  float mean = s * (1.f/1024.f);
  float rstd = rsqrtf(q*(1.f/1024.f) - mean*mean + 1e-5f);
  float amax = 0.f;
  #pragma unroll
  for (int jj = 0; jj < 16; ++jj) amax = fmaxf(amax, fabsf(f[jj]-mean));
  #pragma unroll
  for (int d = 32; d; d >>= 1) amax = fmaxf(amax, __shfl_xor(amax, d));
  amax *= rstd;
  float inv = (amax > 0.f) ? 127.f/amax : 0.f;
  if (l == 0) sca[row] = amax * (1.f/127.f);
  uint32_t wds[4];
  #pragma unroll
  for (int i = 0; i < 4; ++i){
    uint32_t wd = 0;
    #pragma unroll
    for (int c = 0; c < 4; ++c){
      int qv = (int)rintf((f[i*4+c]-mean)*rstd*inv);
      wd |= ((uint32_t)(uint8_t)(int8_t)qv) << (c*8);
    }
    wds[i] = wd;
  }
  int4v pk; pk[0]=(int)wds[0]; pk[1]=(int)wds[1]; pk[2]=(int)wds[2]; pk[3]=(int)wds[3];
  *(int4v*)(outp + (size_t)row*1024 + l*16) = pk;
}

// ---------------- rownorm f32 -> i8 + per-row scale ------------------------
__global__ __launch_bounds__(256) void k_rownorm_f32_i8(const float* __restrict__ in,
        int8_t* __restrict__ outp, float* __restrict__ sca){
  int w = threadIdx.x >> 6, l = threadIdx.x & 63;
  int row = blockIdx.x*4 + w;
  const float* rp = in + (size_t)row*1024 + l*16;
  float f[16]; float s = 0.f, q = 0.f;
  #pragma unroll
  for (int i = 0; i < 4; ++i){
    float4 v = *(const float4*)(rp + i*4);
    f[i*4+0] = v.x; f[i*4+1] = v.y; f[i*4+2] = v.z; f[i*4+3] = v.w;
  }
  #pragma unroll
  for (int jj = 0; jj < 16; ++jj){ s += f[jj]; q += f[jj]*f[jj]; }
  wreduce2(s, q);
  float mean = s * (1.f/1024.f);
  float rstd = rsqrtf(q*(1.f/1024.f) - mean*mean + 1e-5f);
  float amax = 0.f;
  #pragma unroll
  for (int jj = 0; jj < 16; ++jj) amax = fmaxf(amax, fabsf(f[jj]-mean));
  #pragma unroll
  for (int d = 32; d; d >>= 1) amax = fmaxf(amax, __shfl_xor(amax, d));
  amax *= rstd;
  float inv = (amax > 0.f) ? 127.f/amax : 0.f;
  if (l == 0) sca[row] = amax * (1.f/127.f);
  uint32_t wds[4];
  #pragma unroll
  for (int i = 0; i < 4; ++i){
    uint32_t wd = 0;
    #pragma unroll
    for (int c = 0; c < 4; ++c){
      int qv = (int)rintf((f[i*4+c]-mean)*rstd*inv);
      wd |= ((uint32_t)(uint8_t)(int8_t)qv) << (c*8);
    }
    wds[i] = wd;
  }
  int4v pk; pk[0]=(int)wds[0]; pk[1]=(int)wds[1]; pk[2]=(int)wds[2]; pk[3]=(int)wds[3];
  *(int4v*)(outp + (size_t)row*1024 + l*16) = pk;
}

// ---------------- bf16 rows -> i8 + per-row scale (no norm) ----------------
template<int PER>
__global__ __launch_bounds__(256) void k_quant_rows(const ushort_t* __restrict__ in,
        int8_t* __restrict__ outp, float* __restrict__ sca){
  const int K = PER*64;
  int w = threadIdx.x >> 6, l = threadIdx.x & 63;
  int row = blockIdx.x*4 + w;
  const ushort_t* rp = in + (size_t)row*K + l*PER;
  float f[PER];
  #pragma unroll
  for (int i = 0; i < PER/4; ++i){
    ushort4v u = *(const ushort4v*)(rp + i*4);
    f[i*4+0] = bf2f(u.x); f[i*4+1] = bf2f(u.y);
    f[i*4+2] = bf2f(u.z); f[i*4+3] = bf2f(u.w);
  }
  float amax = 0.f;
  #pragma unroll
  for (int jj = 0; jj < PER; ++jj) amax = fmaxf(amax, fabsf(f[jj]));
  #pragma unroll
  for (int d = 32; d; d >>= 1) amax = fmaxf(amax, __shfl_xor(amax, d));
  float inv = (amax > 0.f) ? 127.f/amax : 0.f;
  if (l == 0) sca[row] = amax * (1.f/127.f);
  #pragma unroll
  for (int vq = 0; vq < PER/16; ++vq){
    int4v pk;
    #pragma unroll
    for (int i = 0; i < 4; ++i){
      uint32_t wd = 0;
      #pragma unroll
      for (int c = 0; c < 4; ++c){
        int qv = (int)rintf(f[vq*16 + i*4 + c]*inv);
        wd |= ((uint32_t)(uint8_t)(int8_t)qv) << (c*8);
      }
      pk[i] = (int)wd;
    }
    *(int4v*)(outp + (size_t)row*K + l*PER + vq*16) = pk;
  }
}

// ---------------- final layernorm (affine) f32 -> f32 ----------------------
__global__ __launch_bounds__(256) void k_final_ln(const float* __restrict__ x,
        const float* __restrict__ g, const float* __restrict__ bb, float* __restrict__ outp){
  int w = threadIdx.x >> 6, l = threadIdx.x & 63;
  int row = blockIdx.x*4 + w;
  const float* rp = x + (size_t)row*1024;
  float4 v[4]; float s = 0.f, q = 0.f;
  #pragma unroll
  for (int i = 0; i < 4; ++i){
    v[i] = *(const float4*)(rp + i*256 + l*4);
    s += v[i].x+v[i].y+v[i].z+v[i].w;
    q += v[i].x*v[i].x+v[i].y*v[i].y+v[i].z*v[i].z+v[i].w*v[i].w;
  }
  wreduce2(s, q);
  float mean = s * (1.f/1024.f);
  float rstd = rsqrtf(q*(1.f/1024.f) - mean*mean + 1e-5f);
  float* op = outp + (size_t)row*1024;
  #pragma unroll
  for (int i = 0; i < 4; ++i){
    float4 gg = *(const float4*)(g + i*256 + l*4);
    float4 bv = *(const float4*)(bb + i*256 + l*4);
    float4 o;
    o.x = (v[i].x-mean)*rstd*gg.x + bv.x; o.y = (v[i].y-mean)*rstd*gg.y + bv.y;
    o.z = (v[i].z-mean)*rstd*gg.z + bv.z; o.w = (v[i].w-mean)*rstd*gg.w + bv.w;
    *(float4*)(op + i*256 + l*4) = o;
  }
}

// ---------------- x init ----------------------------------------------------
__global__ __launch_bounds__(256) void k_init_x(const float* __restrict__ lat, float* __restrict__ x){
  int v = blockIdx.x*256 + threadIdx.x;
  int row = v >> 8, cv = v & 255;
  ((float4*)x)[v] = ((const float4*)lat)[(row & 63)*256 + cv];
}

// ---------------- batched weight fold + transpose --------------------------
DEV void foldT_body(const float* __restrict__ W, const float* __restrict__ g,
                    float scale, ushort_t* __restrict__ Wt, int K, int N,
                    int n0, int k0){
  __shared__ float Ts[64][65];
  int t = threadIdx.x;
  #pragma unroll
  for (int i = 0; i < 4; ++i){
    int flat = i*1024 + t*4; int r = flat >> 6, c = flat & 63;
    float4 v = *(const float4*)(W + (size_t)(k0+r)*N + n0 + c);
    float gg = (g ? g[k0+r] : 1.f) * scale;
    Ts[r][c] = v.x*gg; Ts[r][c+1] = v.y*gg; Ts[r][c+2] = v.z*gg; Ts[r][c+3] = v.w*gg;
  }
  __syncthreads();
  #pragma unroll
  for (int i = 0; i < 4; ++i){
    int flat = i*1024 + t*4; int rn = flat >> 6, ck = flat & 63;
    ushort4v o;
    o.x = f2bf(Ts[ck][rn]);   o.y = f2bf(Ts[ck+1][rn]);
    o.z = f2bf(Ts[ck+2][rn]); o.w = f2bf(Ts[ck+3][rn]);
    *(ushort4v*)(Wt + (size_t)(n0+rn)*K + k0 + ck) = o;
  }
}

struct FDesc { const float* W; const float* g; ushort_t* dst; float scale; int K; int N; };
#define MAXFD 32
struct FoldTArgs { int cnt; FDesc d[MAXFD]; };

__global__ __launch_bounds__(256) void k_foldT_all(FoldTArgs a){
  const FDesc d = a.d[blockIdx.y];
  int nxb = d.N >> 6;
  int n0 = (blockIdx.x % nxb) * 64;
  int k0 = (blockIdx.x / nxb) * 64;
  if (k0 >= d.K) return;
  foldT_body(d.W, d.g, d.scale, d.dst, d.K, d.N, n0, k0);
}

// ---------------- batched bias fold ----------------------------------------
DEV void foldBias_body(const float* __restrict__ W, const float* __restrict__ bvec,
                       float scale, float* __restrict__ bias, int K, int N, int o0){
  int t = threadIdx.x;
  int ol = t & 31, kc = t >> 5;
  int o = o0 + ol;
  int chunk = K >> 3;
  int c0 = kc*chunk, c1 = c0 + chunk;
  float s0 = 0, s1 = 0, s2 = 0, s3 = 0;
  for (int c = c0; c < c1; c += 4){
    s0 += bvec[c+0]*W[(size_t)(c+0)*N + o];
    s1 += bvec[c+1]*W[(size_t)(c+1)*N + o];
    s2 += bvec[c+2]*W[(size_t)(c+2)*N + o];
    s3 += bvec[c+3]*W[(size_t)(c+3)*N + o];
  }
  __shared__ float red[8][32];
  red[kc][ol] = (s0+s1)+(s2+s3);
  __syncthreads();
  if (kc == 0){
    float tot = 0;
    #pragma unroll
    for (int jj = 0; jj < 8; ++jj) tot += red[jj][ol];
    bias[o] = tot * scale;
  }
}

struct BDesc { const float* W; const float* b; float* dst; float scale; int K; int N; };
#define MAXBD 25
struct BiasArgs { int cnt; BDesc d[MAXBD]; };

__global__ __launch_bounds__(256) void k_foldBias_all(BiasArgs a){
  const BDesc d = a.d[blockIdx.y];
  int o0 = blockIdx.x * 32;
  if (o0 >= d.N) return;
  foldBias_body(d.W, d.b, d.scale, d.dst, d.K, d.N, o0);
}

// ---------------- 64-row i8 GEMM (small shapes) ----------------------------
template<int OUTMODE, int BN>
__global__ __launch_bounds__(256, 4) void k_gemm_sm(const int8_t* __restrict__ A,
        const int8_t* __restrict__ Bt, const float* __restrict__ sAr,
        const float* __restrict__ sBr, const float* __restrict__ bias,
        void* __restrict__ Cp, int M, int N, int Kb){
  constexpr int BM = 64;
  constexpr int NIF = BN/32;
  const int n0 = blockIdx.x * BN;
  const int m0 = blockIdx.y * BM;
  __shared__ __align__(16) char sA[2][BM*64];
  __shared__ __align__(16) char sB[2][BN*64];
  const int tid = threadIdx.x;
  const int wave = tid >> 6, lane = tid & 63;
  const int lo = lane & 15, hi = lane >> 4;
  const int wr = wave >> 1, wc = wave & 1;

  auto stage = [&](int buf, int k0){
    {
      int r = tid >> 2;
      int c = (tid & 3) ^ (r & 3);
      const int8_t* gp = A + (size_t)(m0 + r)*Kb + k0 + c*16;
      GLOAD16(gp, &sA[buf][0] + tid*16);
    }
    #pragma unroll
    for (int p = 0; p < BN/64; ++p){
      int r = p*64 + (tid >> 2);
      int c = (tid & 3) ^ (r & 3);
      const int8_t* gp = Bt + (size_t)(n0 + r)*Kb + k0 + c*16;
      GLOAD16(gp, &sB[buf][0] + p*4096 + tid*16);
    }
  };

  int4v acc[2][NIF] = {};
  stage(0, 0);
  const int nk = Kb >> 6;
  for (int ks = 0; ks < nk; ++ks){
    __syncthreads();
    if (ks + 1 < nk) stage((ks+1)&1, (ks+1) << 6);
    const int buf = ks & 1;
    int4v af[2], bfr[NIF];
    #pragma unroll
    for (int mi = 0; mi < 2; ++mi){
      int row = wr*(BM/2) + mi*16 + lo;
      af[mi] = *(const int4v*)(&sA[buf][row*64 + ((hi ^ (row & 3))*16)]);
    }
    #pragma unroll
    for (int ni = 0; ni < NIF; ++ni){
      int row = wc*(BN/2) + ni*16 + lo;
      bfr[ni] = *(const int4v*)(&sB[buf][row*64 + ((hi ^ (row & 3))*16)]);
    }
    #pragma unroll
    for (int mi = 0; mi < 2; ++mi)
      #pragma unroll
      for (int ni = 0; ni < NIF; ++ni)
        acc[mi][ni] = MFMAI8(af[mi], bfr[ni], acc[mi][ni]);
  }
  #pragma unroll
  for (int ni = 0; ni < NIF; ++ni){
    int col = n0 + wc*(BN/2) + ni*16 + lo;
    float bv = bias ? bias[col] : 0.f;
    float sb = sBr[col];
    #pragma unroll
    for (int mi = 0; mi < 2; ++mi){
      int rbase = m0 + wr*(BM/2) + mi*16 + hi*4;
      #pragma unroll
      for (int rr = 0; rr < 4; ++rr){
        int row = rbase + rr;
        float v = (float)acc[mi][ni][rr] * (sAr[row]*sb) + bv;
        size_t off = (size_t)row*N + col;
        if (OUTMODE == 0)      ((ushort_t*)Cp)[off] = f2bf(v);
        else if (OUTMODE == 1) ((ushort_t*)Cp)[off] = f2bf(fmaxf(v, 0.f));
        else                   ((float*)Cp)[off] += v;
      }
    }
  }
}

// ---------------- 256x256 8-phase bf16 GEMM (down-proj) --------------------
template<bool SKIP, int NXB>
__global__ __launch_bounds__(512, 2) void k_gemm256p8(const ushort_t* __restrict__ A,
        const ushort_t* __restrict__ Bt, const float* __restrict__ bias,
        ushort_t* __restrict__ Cp, int M, int N, int K, const int* __restrict__ cnt){
  int bx, by;
  xcd_remapN<NXB>(blockIdx.x, gridDim.x, bx, by);
  const int n0 = bx * 256;
  const int m0 = by * 256;
  if (SKIP){ int b = m0 >> 11; if ((m0 & 2047) >= cnt[b]) return; }
  __shared__ __align__(16) ushort_t sA[2][256*64];
  __shared__ __align__(16) ushort_t sB[2][256*64];
  const int tid = threadIdx.x;
  const int wave = tid >> 6, lane = tid & 63;
  const int lo = lane & 15, hi = lane >> 4;
  const int wm = wave >> 2, wn = wave & 3;
  const int srow = lane >> 3;
  const int schunk = (lane & 7) ^ srow;
  auto stageHalf = [&](ushort_t* dst, const ushort_t* __restrict__ G, int grow0,
                       int half, int k0){
    #pragma unroll
    for (int p = 0; p < 2; ++p){
      int rbase = half*128 + p*64 + wave*8;
      const ushort_t* gp = G + (size_t)(grow0 + rbase + srow)*K + k0 + schunk*8;
      char* lp = (char*)dst + (size_t)rbase*128;
      GLOAD16(gp, lp);
    }
  };
  auto ldsA = [&](int buf, int row, int kk)->short8{
    int ch = ((kk<<2) + hi) ^ (row & 7);
    return *(const short8*)((const char*)sA + (size_t)buf*32768 + (size_t)row*128 + ch*16);
  };
  auto ldsB = [&](int buf, int row, int kk)->short8{
    int ch = ((kk<<2) + hi) ^ (row & 7);
    return *(const short8*)((const char*)sB + (size_t)buf*32768 + (size_t)row*128 + ch*16);
  };
  f32x4 acc[8][4] = {};

  short8 af[4][2], bg[2][2];
#define LOADA(BUF, AH) \
    _Pragma("unroll") for (int mi_ = 0; mi_ < 4; ++mi_) \
      _Pragma("unroll") for (int kk_ = 0; kk_ < 2; ++kk_) \
        af[mi_][kk_] = ldsA(BUF, (AH)*128 + wm*64 + mi_*16 + lo, kk_);
#define LOADB(BUF, BH) \
    _Pragma("unroll") for (int nj_ = 0; nj_ < 2; ++nj_) \
      _Pragma("unroll") for (int kk_ = 0; kk_ < 2; ++kk_) \
        bg[nj_][kk_] = ldsB(BUF, (BH)*128 + wn*32 + nj_*16 + lo, kk_);
#define MMQ(AH, BH) \
    __builtin_amdgcn_s_barrier(); CFENCE; \
    __builtin_amdgcn_s_setprio(1); \
    _Pragma("unroll") for (int mi_ = 0; mi_ < 4; ++mi_) \
      _Pragma("unroll") for (int nj_ = 0; nj_ < 2; ++nj_) \
        _Pragma("unroll") for (int kk_ = 0; kk_ < 2; ++kk_) \
          acc[(AH)*4+mi_][(BH)*2+nj_] = \
            MFMA16(af[mi_][kk_], bg[nj_][kk_], acc[(AH)*4+mi_][(BH)*2+nj_]); \
    __builtin_amdgcn_s_setprio(0); CFENCE; \
    __builtin_amdgcn_s_barrier(); CFENCE;

  stageHalf(&sA[0][0], A,  m0, 0, 0);
  stageHalf(&sB[0][0], Bt, n0, 0, 0);
  stageHalf(&sA[0][0], A,  m0, 1, 0);
  stageHalf(&sB[0][0], Bt, n0, 1, 0);
  stageHalf(&sA[1][0], A,  m0, 0, 64);
  stageHalf(&sB[1][0], Bt, n0, 1, 64);
  VMCNT(4);
  __builtin_amdgcn_s_barrier();
  CFENCE;

  const int NI = K >> 7;
  for (int i = 0; i < NI; ++i){
    const int kt = i << 7;
    const bool lastI = (i == NI-1);
    LOADA(0,0) LOADB(0,0)
    stageHalf(&sA[1][0], A,  m0, 1, kt+64);
    MMQ(0,0)
    LOADB(0,1)
    stageHalf(&sB[1][0], Bt, n0, 0, kt+64);
    MMQ(0,1)
    LOADA(0,1)
    if (!lastI) stageHalf(&sA[0][0], A,  m0, 0, kt+128);
    MMQ(1,1)
    LOADB(0,0)
    if (!lastI) stageHalf(&sB[0][0], Bt, n0, 1, kt+128);
    if (lastI){ VMCNT(0); } else { VMCNT(4); }
    MMQ(1,0)
    LOADA(1,0) LOADB(1,0)
    if (!lastI) stageHalf(&sA[0][0], A,  m0, 1, kt+128);
    MMQ(0,0)
    LOADB(1,1)
    if (!lastI) stageHalf(&sB[0][0], Bt, n0, 0, kt+128);
    MMQ(0,1)
    LOADA(1,1)
    if (!lastI) stageHalf(&sA[1][0], A,  m0, 0, kt+192);
    MMQ(1,1)
    LOADB(1,0)
    if (!lastI){ stageHalf(&sB[1][0], Bt, n0, 1, kt+192); VMCNT(4); }
    MMQ(1,0)
  }
#undef LOADA
#undef LOADB
#undef MMQ

  #pragma unroll
  for (int b2 = 0; b2 < 2; ++b2)
    #pragma unroll
    for (int nj = 0; nj < 2; ++nj){
      int col = n0 + b2*128 + wn*32 + nj*16 + lo;
      float bv = bias ? bias[col] : 0.f;
      #pragma unroll
      for (int a2 = 0; a2 < 2; ++a2)
        #pragma unroll
        for (int mi4 = 0; mi4 < 4; ++mi4){
          int rbase = m0 + a2*128 + wm*64 + mi4*16 + hi*4;
          #pragma unroll
          for (int rr = 0; rr < 4; ++rr){
            float v = acc[a2*4+mi4][b2*2+nj][rr] + bv;
            Cp[(size_t)(rbase + rr)*N + col] = f2bf(v);
          }
        }
    }
}

// ---------------- 256x256 8-phase i8 GEMM (KV projections) -----------------
template<bool SKIP, int NXB>
__global__ __launch_bounds__(512, 2) void k_gemm256i8(const int8_t* __restrict__ A,
        const int8_t* __restrict__ Bt, const float* __restrict__ sAr,
        const float* __restrict__ sBr, const float* __restrict__ bias,
        ushort_t* __restrict__ Cp, int M, int N, int Kb, const int* __restrict__ cnt){
  int bx, by;
  xcd_remapN<NXB>(blockIdx.x, gridDim.x, bx, by);
  const int n0 = bx * 256;
  const int m0 = by * 256;
  if (SKIP){ int b = m0 >> 11; if ((m0 & 2047) >= cnt[b]) return; }
  __shared__ __align__(16) char sAl[2][256*128];
  __shared__ __align__(16) char sBl[2][256*128];
  const int tid = threadIdx.x;
  const int wave = tid >> 6, lane = tid & 63;
  const int lo = lane & 15, hi = lane >> 4;
  const int wm = wave >> 2, wn = wave & 3;
  const int srow = lane >> 3;
  const int schunk = (lane & 7) ^ srow;
  auto stageHalf = [&](char* dst, const int8_t* __restrict__ G, int grow0,
                       int half, int k0){            // k0 in BYTES
    #pragma unroll
    for (int p = 0; p < 2; ++p){
      int rbase = half*128 + p*64 + wave*8;
      const int8_t* gp = G + (size_t)(grow0 + rbase + srow)*Kb + k0 + schunk*16;
      char* lp = dst + (size_t)rbase*128;
      GLOAD16(gp, lp);
    }
  };
  auto ldsA = [&](int buf, int row, int kk)->int4v{
    int ch = ((kk<<2) + hi) ^ (row & 7);
    return *(const int4v*)((const char*)sAl + (size_t)buf*32768 + (size_t)row*128 + ch*16);
  };
  auto ldsB = [&](int buf, int row, int kk)->int4v{
    int ch = ((kk<<2) + hi) ^ (row & 7);
    return *(const int4v*)((const char*)sBl + (size_t)buf*32768 + (size_t)row*128 + ch*16);
  };
  int4v acc[8][4] = {};

  int4v af[4][2], bg[2][2];
#define LOADA(BUF, AH) \
    _Pragma("unroll") for (int mi_ = 0; mi_ < 4; ++mi_) \
      _Pragma("unroll") for (int kk_ = 0; kk_ < 2; ++kk_) \
        af[mi_][kk_] = ldsA(BUF, (AH)*128 + wm*64 + mi_*16 + lo, kk_);
#define LOADB(BUF, BH) \
    _Pragma("unroll") for (int nj_ = 0; nj_ < 2; ++nj_) \
      _Pragma("unroll") for (int kk_ = 0; kk_ < 2; ++kk_) \
        bg[nj_][kk_] = ldsB(BUF, (BH)*128 + wn*32 + nj_*16 + lo, kk_);
#define MMQ(AH, BH) \
    __builtin_amdgcn_s_barrier(); CFENCE; \
    __builtin_amdgcn_s_setprio(1); \
    _Pragma("unroll") for (int mi_ = 0; mi_ < 4; ++mi_) \
      _Pragma("unroll") for (int nj_ = 0; nj_ < 2; ++nj_) \
        _Pragma("unroll") for (int kk_ = 0; kk_ < 2; ++kk_) \
          acc[(AH)*4+mi_][(BH)*2+nj_] = \
            MFMAI8(af[mi_][kk_], bg[nj_][kk_], acc[(AH)*4+mi_][(BH)*2+nj_]); \
    __builtin_amdgcn_s_setprio(0); CFENCE; \
    __builtin_amdgcn_s_barrier(); CFENCE;

  stageHalf(&sAl[0][0], A,  m0, 0, 0);
  stageHalf(&sBl[0][0], Bt, n0, 0, 0);
  stageHalf(&sAl[0][0], A,  m0, 1, 0);
  stageHalf(&sBl[0][0], Bt, n0, 1, 0);
  stageHalf(&sAl[1][0], A,  m0, 0, 128);
  stageHalf(&sBl[1][0], Bt, n0, 1, 128);
  VMCNT(4);
  __builtin_amdgcn_s_barrier();
  CFENCE;

  const int NI = Kb >> 8;
  for (int i = 0; i < NI; ++i){
    const int kt = i << 8;
    const bool lastI = (i == NI-1);
    LOADA(0,0) LOADB(0,0)
    stageHalf(&sAl[1][0], A,  m0, 1, kt+128);
    MMQ(0,0)
    LOADB(0,1)
    stageHalf(&sBl[1][0], Bt, n0, 0, kt+128);
    MMQ(0,1)
    LOADA(0,1)
    if (!lastI) stageHalf(&sAl[0][0], A,  m0, 0, kt+256);
    MMQ(1,1)
    LOADB(0,0)
    if (!lastI) stageHalf(&sBl[0][0], Bt, n0, 1, kt+256);
    if (lastI){ VMCNT(0); } else { VMCNT(4); }
    MMQ(1,0)
    LOADA(1,0) LOADB(1,0)
    if (!lastI) stageHalf(&sAl[0][0], A,  m0, 1, kt+256);
    MMQ(0,0)
    LOADB(1,1)
    if (!lastI) stageHalf(&sBl[0][0], Bt, n0, 0, kt+256);
    MMQ(0,1)
    LOADA(1,1)
    if (!lastI) stageHalf(&sAl[1][0], A,  m0, 0, kt+384);
    MMQ(1,1)
    LOADB(1,0)
    if (!lastI){ stageHalf(&sBl[1][0], Bt, n0, 1, kt+384); VMCNT(4); }
    MMQ(1,0)
  }
#undef LOADA
#undef LOADB
#undef MMQ

  #pragma unroll
  for (int b2 = 0; b2 < 2; ++b2)
    #pragma unroll
    for (int nj = 0; nj < 2; ++nj){
      int col = n0 + b2*128 + wn*32 + nj*16 + lo;
      float bv = bias ? bias[col] : 0.f;
      float sb = sBr[col];
      #pragma unroll
      for (int a2 = 0; a2 < 2; ++a2)
        #pragma unroll
        for (int mi4 = 0; mi4 < 4; ++mi4){
          int rbase = m0 + a2*128 + wm*64 + mi4*16 + hi*4;
          #pragma unroll
          for (int rr = 0; rr < 4; ++rr){
            int row = rbase + rr;
            float v = (float)acc[a2*4+mi4][b2*2+nj][rr] * (sAr[row]*sb) + bv;
            Cp[(size_t)row*N + col] = f2bf(v);
          }
        }
    }
}

// ---------------- flash attention, split over 2 key-chunks -----------------
// grid = 1024: chunk = blockIdx.x & 1 (keys [c*1024, c*1024+1024) of count),
// bh = blockIdx.x >> 1. Writes UNNORMALIZED partial O (f32) + per-(row,head)
// m,l to scratch; k_combine merges.
__global__ __launch_bounds__(256) void k_attn_split(const ushort_t* __restrict__ qb,
        const ushort_t* __restrict__ kvb, int kstride, const int* __restrict__ cnt,
        float* __restrict__ PO, float* __restrict__ PM, float* __restrict__ PL){
  const int c = blockIdx.x & 1;
  const int bh = blockIdx.x >> 1;
  const int b = bh >> 4, h = bh & 15;
  const int t = threadIdx.x;
  const int wave = t >> 6, lane = t & 63, lo = lane & 15, hi = lane >> 4;
  __shared__ ushort_t Qs[64*64];
  __shared__ ushort_t Ks[2][64*64];
  __shared__ ushort_t Vt[2][64][72];
  __shared__ ushort_t Ps[4][16][72];

  const int count = cnt[b];
  const int kbase = c * 1024;
  int rem = count - kbase;
  const int ntiles = (rem > 0) ? ((rem + 63) >> 6 < 16 ? (rem + 63) >> 6 : 16) : 0;

  // stage Q (gload_lds, pre-swizzled source chunks)
  #pragma unroll
  for (int p = 0; p < 2; ++p){
    int r = p*32 + wave*8 + (lane >> 3);
    int cc = (lane & 7) ^ (r & 7);
    const ushort_t* gp = qb + (size_t)(b*64 + r)*1024 + h*64 + cc*8;
    char* lp = (char*)Qs + p*4096 + wave*1024;
    GLOAD16(gp, lp);
  }

  auto stageK = [&](int buf, int tt){
    #pragma unroll
    for (int p = 0; p < 2; ++p){
      int r = p*32 + wave*8 + (lane >> 3);
      int cc = (lane & 7) ^ (r & 7);
      const ushort_t* gp = kvb + (size_t)(b*2048 + kbase + tt*64 + r)*kstride + h*64 + cc*8;
      char* lp = (char*)(&Ks[buf][0]) + p*4096 + wave*1024;
      GLOAD16(gp, lp);
    }
  };
  const int vjj = (t & 31)*2, vc = (t >> 5)*8;
  ushort4v va0, va1, vb0, vb1;
  auto issueV = [&](int tt){
    const ushort_t* g0 = kvb + (size_t)(b*2048 + kbase + tt*64 + vjj)*kstride + 1024 + h*64 + vc;
    va0 = *(const ushort4v*)(g0);
    va1 = *(const ushort4v*)(g0 + 4);
    vb0 = *(const ushort4v*)(g0 + kstride);
    vb1 = *(const ushort4v*)(g0 + kstride + 4);
  };
  auto writeV = [&](int buf, int tt){
    bool va  = (kbase + tt*64 + vjj)     < count;
    bool vb2 = (kbase + tt*64 + vjj + 1) < count;
    #pragma unroll
    for (int u = 0; u < 8; ++u){
      ushort_t ea = (u < 4) ? ((ushort_t*)&va0)[u] : ((ushort_t*)&va1)[u-4];
      ushort_t eb = (u < 4) ? ((ushort_t*)&vb0)[u] : ((ushort_t*)&vb1)[u-4];
      uint32_t word = (va ? (uint32_t)ea : 0u) | ((vb2 ? (uint32_t)eb : 0u) << 16);
      *(uint32_t*)(&Vt[buf][vc+u][vjj]) = word;
    }
  };

  f32x4 oacc[4] = {};
  float m[4], l[4];
  #pragma unroll
  for (int rr = 0; rr < 4; ++rr){ m[rr] = -__builtin_inff(); l[rr] = 0.f; }

  if (ntiles > 0){ stageK(0, 0); issueV(0); }

  for (int tt = 0; tt < ntiles; ++tt){
    const int buf = tt & 1;
    writeV(buf, tt);                          // implicit vmcnt wait drains K(tt)
    if (tt + 1 < ntiles){ stageK(buf^1, tt+1); issueV(tt+1); }
    asm volatile("s_waitcnt lgkmcnt(0)" ::: "memory");
    __builtin_amdgcn_s_barrier();
    CFENCE;

    f32x4 s[4] = {};
    #pragma unroll
    for (int kk = 0; kk < 2; ++kk){
      int rA = wave*16 + lo;
      short8 aq = *(const short8*)(&Qs[rA*64 + (((kk*4 + hi) ^ (rA & 7))*8)]);
      #pragma unroll
      for (int ni = 0; ni < 4; ++ni){
        int rB = ni*16 + lo;
        short8 bk = *(const short8*)(&Ks[buf][rB*64 + (((kk*4 + hi) ^ (rB & 7))*8)]);
        s[ni] = MFMA16(aq, bk, s[ni]);
      }
    }
    #pragma unroll
    for (int ni = 0; ni < 4; ++ni){
      if (kbase + tt*64 + ni*16 + lo >= count){
        s[ni][0] = s[ni][1] = s[ni][2] = s[ni][3] = -__builtin_inff();
      }
    }
    float p[4][4];
    #pragma unroll
    for (int rr = 0; rr < 4; ++rr){
      float mx = fmaxf(fmaxf(s[0][rr], s[1][rr]), fmaxf(s[2][rr], s[3][rr]));
      #pragma unroll
      for (int d = 1; d < 16; d <<= 1) mx = fmaxf(mx, __shfl_xor(mx, d));
      float mnew = fmaxf(m[rr], mx);
      float sc = __expf(m[rr] - mnew);
      float rsum = 0.f;
      #pragma unroll
      for (int ni = 0; ni < 4; ++ni){
        float pv = __expf(s[ni][rr] - mnew);
        p[ni][rr] = pv;
        rsum += pv;
      }
      #pragma unroll
      for (int d = 1; d < 16; d <<= 1) rsum += __shfl_xor(rsum, d);
      l[rr] = l[rr]*sc + rsum;
      m[rr] = mnew;
      #pragma unroll
      for (int ni = 0; ni < 4; ++ni) oacc[ni][rr] *= sc;
    }
    #pragma unroll
    for (int ni = 0; ni < 4; ++ni)
      #pragma unroll
      for (int rr = 0; rr < 4; ++rr)
        Ps[wave][hi*4+rr][ni*16+lo] = f2bf(p[ni][rr]);
    asm volatile("s_waitcnt lgkmcnt(0)" ::: "memory");
    #pragma unroll
    for (int kk = 0; kk < 2; ++kk){
      short8 pa = *(const short8*)(&Ps[wave][lo][kk*32 + hi*8]);
      #pragma unroll
      for (int ni = 0; ni < 4; ++ni){
        short8 bv = *(const short8*)(&Vt[buf][ni*16 + lo][kk*32 + hi*8]);
        oacc[ni] = MFMA16(pa, bv, oacc[ni]);
      }
    }
    CFENCE;
    __builtin_amdgcn_s_barrier();
    CFENCE;
  }
  // write partials (unnormalized)
  #pragma unroll
  for (int rr = 0; rr < 4; ++rr){
    int row = b*64 + wave*16 + hi*4 + rr;
    if (lo == 0){
      PM[(size_t)(c*2048 + row)*16 + h] = m[rr];
      PL[(size_t)(c*2048 + row)*16 + h] = l[rr];
    }
    #pragma unroll
    for (int ni = 0; ni < 4; ++ni){
      PO[(size_t)(c*2048 + row)*1024 + h*64 + ni*16 + lo] = oacc[ni][rr];
    }
  }
}

// ---------------- combine 2 attention chunks -> bf16 out -------------------
__global__ __launch_bounds__(256) void k_combine(const float* __restrict__ PO,
        const float* __restrict__ PM, const float* __restrict__ PL,
        ushort_t* __restrict__ outb){
  int w = threadIdx.x >> 6, l = threadIdx.x & 63;
  int row = blockIdx.x*4 + w;
  int h = l >> 2, d0 = (l & 3)*16;
  float m0 = PM[(size_t)row*16 + h],        l0 = PL[(size_t)row*16 + h];
  float m1 = PM[(size_t)(2048 + row)*16 + h], l1 = PL[(size_t)(2048 + row)*16 + h];
  float M = fmaxf(m0, m1);
  float e0 = (l0 > 0.f) ? __expf(m0 - M) : 0.f;
  float e1 = (l1 > 0.f) ? __expf(m1 - M) : 0.f;
  float L = l0*e0 + l1*e1;
  float inv = (L > 0.f) ? 1.f/L : 0.f;
  const float* p0 = PO + (size_t)row*1024 + h*64 + d0;
  const float* p1 = PO + (size_t)(2048 + row)*1024 + h*64 + d0;
  ushort_t* op = outb + (size_t)row*1024 + h*64 + d0;
  #pragma unroll
  for (int i = 0; i < 4; ++i){
    float4 a = *(const float4*)(p0 + i*4);
    float4 bq = *(const float4*)(p1 + i*4);
    ushort4v o;
    o.x = f2bf((a.x*e0 + bq.x*e1)*inv);
    o.y = f2bf((a.y*e0 + bq.y*e1)*inv);
    o.z = f2bf((a.z*e0 + bq.z*e1)*inv);
    o.w = f2bf((a.w*e0 + bq.w*e1)*inv);
    *(ushort4v*)(op + i*4) = o;
  }
}

// ---------------------------------------------------------------------------
extern "C" void kernel_launch(void* const* d_in, const int* in_sizes, int n_in,
                              void* d_out, int out_size, void* d_ws, size_t ws_size,
                              hipStream_t stream){
  const float* features = (const float*)d_in[0];
  const int*   mask     = (const int*)  d_in[1];
  const float* latents  = (const float*)d_in[2];
  const float* W_down   = (const float*)d_in[3];
  const float* nin_g    = (const float*)d_in[4];
  const float* nin_b    = (const float*)d_in[5];
  const float* lf_g     = (const float*)d_in[6];
  const float* lf_b     = (const float*)d_in[7];
  const float* ll_g     = (const float*)d_in[8];
  const float* ll_b     = (const float*)d_in[9];
  const float* Wq       = (const float*)d_in[10];
  const float* Wk       = (const float*)d_in[11];
  const float* Wv       = (const float*)d_in[12];
  const float* ffln_g   = (const float*)d_in[13];
  const float* ffln_b   = (const float*)d_in[14];
  const float* ff_w1    = (const float*)d_in[15];
  const float* ff_w2    = (const float*)d_in[16];
  const float* nout_g   = (const float*)d_in[17];
  const float* nout_b   = (const float*)d_in[18];

  char* ws = (char*)d_ws;
  size_t off = 0;
  auto alloc = [&](size_t bytes)->char*{
    char* p = ws + off;
    off += (bytes + 255) & ~(size_t)255;
    return p;
  };
  const size_t SZW = (size_t)1024*1024*2;       // 2 MB (1024x1024 bf16)

  ushort_t* FHAT  = (ushort_t*)alloc((size_t)65536*1024*2);   // down-proj out
  int8_t*   I8A   = (int8_t*)  alloc((size_t)65536*1024);     // LN'd fhat, i8
  float*    SA    = (float*)   alloc((size_t)65536*4);
  int8_t*   I8KV  = (int8_t*)  alloc((size_t)12288*1024);     // KV weights i8
  float*    SKV   = (float*)   alloc((size_t)12288*4);
  int8_t*   I8Q   = (int8_t*)  alloc((size_t)6144*1024);      // Q weights i8
  float*    SQW   = (float*)   alloc((size_t)6144*4);
  int8_t*   I8W1  = (int8_t*)  alloc((size_t)12288*1024);     // FF1 weights i8
  float*    SW1   = (float*)   alloc((size_t)12288*4);
  int8_t*   I8W2  = (int8_t*)  alloc((size_t)6144*2048);      // FF2 weights i8
  float*    SW2   = (float*)   alloc((size_t)6144*4);
  ushort_t* WDT   = (ushort_t*)alloc(SZW);
  ushort_t* WQT6  = (ushort_t*)alloc(SZW*6);
  ushort_t* WKVT6 = (ushort_t*)alloc(SZW*2*6);
  ushort_t* W1T6  = (ushort_t*)alloc(SZW*2*6);
  ushort_t* W2T6  = (ushort_t*)alloc(SZW*2*6);
  float* BD   = (float*)alloc(1024*4);
  float* BQ6  = (float*)alloc(1024*4*6);
  float* BKV6 = (float*)alloc(2048*4*6);
  float* B16  = (float*)alloc(2048*4*6);
  float*    X    = (float*)   alloc((size_t)2048*1024*4);
  int8_t*   I8X  = (int8_t*)  alloc((size_t)2048*1024);
  float*    SX   = (float*)   alloc((size_t)2048*4);
  ushort_t* QP   = (ushort_t*)alloc((size_t)2048*1024*2);
  ushort_t* OUTB = (ushort_t*)alloc((size_t)2048*1024*2);
  int8_t*   I8O  = (int8_t*)  alloc((size_t)2048*1024);
  float*    SO   = (float*)   alloc((size_t)2048*4);
  ushort_t* H1   = (ushort_t*)alloc((size_t)2048*2048*2);
  int8_t*   I8H  = (int8_t*)  alloc((size_t)2048*2048);
  float*    SH   = (float*)   alloc((size_t)2048*4);
  float*    PO   = (float*)   alloc((size_t)2*2048*1024*4);   // 16 MB partial O
  float*    PM   = (float*)   alloc((size_t)2*2048*16*4);
  float*    PL   = (float*)   alloc((size_t)2*2048*16*4);
  int* CNT = (int*)alloc(32*4);
  int* IDX = (int*)alloc((size_t)65536*4);
  ushort_t* KVBUF = (ushort_t*)alloc((size_t)65536*4096*2);   // 512 MB (2 depths)
  ushort_t* FNORM = KVBUF;   // transient alias (dead before KV GEMM writes)
  (void)in_sizes; (void)n_in; (void)out_size; (void)ws_size;

  const float scale = 0.125f;  // DH^-0.5

  // ---- batched weight folds (all depth-independent) ----
  FoldTArgs fa; int nf = 0;
  auto addF = [&](const float* W, const float* g, float sc, ushort_t* dst, int K, int N){
    fa.d[nf++] = FDesc{W, g, dst, sc, K, N};
  };
  addF(W_down, nin_g, 1.f, WDT, 1024, 1024);
  for (int i = 0; i < 6; ++i){
    const float* Wqi = Wq + (size_t)i*1024*1024;
    const float* Wki = Wk + (size_t)i*1024*1024;
    const float* Wvi = Wv + (size_t)i*1024*1024;
    const float* W1i = ff_w1 + (size_t)i*1024*2048;
    const float* W2i = ff_w2 + (size_t)i*2048*1024;
    addF(Wqi, ll_g + i*1024, scale, WQT6  + i*(SZW/2),        1024, 1024);
    addF(Wki, lf_g + i*1024, 1.f,   WKVT6 + i*SZW,            1024, 1024);
    addF(Wvi, lf_g + i*1024, 1.f,   WKVT6 + i*SZW + (SZW/2),  1024, 1024);
    addF(W1i, ffln_g + i*1024, 1.f, W1T6  + i*SZW,            1024, 2048);
    addF(W2i, nullptr, 1.f,         W2T6  + i*SZW,            2048, 1024);
  }
  fa.cnt = nf;

  BiasArgs ba; int nb = 0;
  auto addB = [&](const float* W, const float* b, float sc, float* dst, int K, int N){
    ba.d[nb++] = BDesc{W, b, dst, sc, K, N};
  };
  addB(W_down, nin_b, 1.f, BD, 1024, 1024);
  for (int i = 0; i < 6; ++i){
    const float* Wqi = Wq + (size_t)i*1024*1024;
    const float* Wki = Wk + (size_t)i*1024*1024;
    const float* Wvi = Wv + (size_t)i*1024*1024;
    const float* W1i = ff_w1 + (size_t)i*1024*2048;
    addB(Wqi, ll_b + i*1024, scale, BQ6  + i*1024,        1024, 1024);
    addB(Wki, lf_b + i*1024, 1.f,   BKV6 + i*2048,        1024, 1024);
    addB(Wvi, lf_b + i*1024, 1.f,   BKV6 + i*2048 + 1024, 1024, 1024);
    addB(W1i, ffln_b + i*1024, 1.f, B16  + i*2048,        1024, 2048);
  }
  ba.cnt = nb;

  // ---- setup ----
  k_compact     <<<32,    256, 0, stream>>>(mask, IDX, CNT);
  k_gather_norm <<<16384, 256, 0, stream>>>(features, IDX, CNT, FNORM);
  k_foldT_all   <<<dim3(512, nf), 256, 0, stream>>>(fa);
  k_foldBias_all<<<dim3(64,  nb), 256, 0, stream>>>(ba);
  k_quant_rows<16><<<3072, 256, 0, stream>>>(WKVT6, I8KV, SKV);
  k_quant_rows<16><<<1536, 256, 0, stream>>>(WQT6,  I8Q,  SQW);
  k_quant_rows<16><<<3072, 256, 0, stream>>>(W1T6,  I8W1, SW1);
  k_quant_rows<32><<<1536, 256, 0, stream>>>(W2T6,  I8W2, SW2);
  k_gemm256p8<true,4><<<1024, 512, 0, stream>>>(FNORM, WDT, BD, FHAT, 65536, 1024, 1024, CNT);
  k_rownorm_i8  <<<16384, 256, 0, stream>>>(FHAT, I8A, SA, CNT);
  k_init_x      <<<2048,  256, 0, stream>>>(latents, X);

  for (int i = 0; i < 6; ++i){
    if ((i & 1) == 0){
      // merged KV projection for depths {i, i+1}: N = 4096
      k_gemm256i8<true,16><<<4096, 512, 0, stream>>>(I8A, I8KV + (size_t)i*2048*1024,
                                                     SA, SKV + i*2048, BKV6 + i*2048,
                                                     KVBUF, 65536, 4096, 1024, CNT);
    }
    k_rownorm_f32_i8<<<512, 256, 0, stream>>>(X, I8X, SX);
    k_gemm_sm<0,64><<<dim3(16,32), 256, 0, stream>>>(I8X, I8Q + (size_t)i*1024*1024,
                                                     SX, SQW + i*1024, BQ6 + i*1024,
                                                     QP, 2048, 1024, 1024);
    k_attn_split<<<1024, 256, 0, stream>>>(QP, KVBUF + (size_t)(i & 1)*2048, 4096,
                                           CNT, PO, PM, PL);
    k_combine<<<512, 256, 0, stream>>>(PO, PM, PL, OUTB);
    k_rownorm_i8<<<512, 256, 0, stream>>>(OUTB, I8O, SO, nullptr);
    k_gemm_sm<1,128><<<dim3(16,32), 256, 0, stream>>>(I8O, I8W1 + (size_t)i*2048*1024,
                                                      SO, SW1 + i*2048, B16 + i*2048,
                                                      H1, 2048, 2048, 1024);
    k_quant_rows<32><<<512, 256, 0, stream>>>(H1, I8H, SH);
    k_gemm_sm<2,64><<<dim3(16,32), 256, 0, stream>>>(I8H, I8W2 + (size_t)i*1024*2048,
                                                     SH, SW2 + i*1024, nullptr,
                                                     X, 2048, 1024, 2048);
  }
  k_final_ln<<<512, 256, 0, stream>>>(X, nout_g, nout_b, (float*)d_out);
}

// Round 12
// 1639.874 us; speedup vs baseline: 1.2414x; 1.2414x over previous
//
#include <hip/hip_runtime.h>
#include <stdint.h>

// ---------------------------------------------------------------------------
// PerceiverResampler on MI355X (gfx950)
// B=32, F=2048, DIM=1024, INNER=1024, H=16, DH=64, Q=64, DEPTH=6, MULT=2
//
// Round 12: full revert to the R10 configuration (best measured: 1641 us,
// absmax 0.0859). R11's merged-KV (N=4096) and split-attention both
// regressed (-35% KV efficiency, strided KV reads, partial-O round-trip).
// ---------------------------------------------------------------------------

#define DEV static __device__ __forceinline__

typedef __attribute__((ext_vector_type(8))) short short8;
typedef __attribute__((ext_vector_type(4))) float f32x4;
typedef __attribute__((ext_vector_type(4))) int int4v;
typedef __attribute__((ext_vector_type(4))) unsigned short ushort4v;
typedef unsigned short ushort_t;

DEV float bf2f(ushort_t u){ union{uint32_t i; float f;} x; x.i = ((uint32_t)u)<<16; return x.f; }
DEV ushort_t f2bf(float f){
  union{float f; uint32_t i;} x; x.f = f;
  uint32_t r = x.i + 0x7fffu + ((x.i>>16)&1u);  // RNE
  return (ushort_t)(r>>16);
}

#define GLOAD16(gp, lp) __builtin_amdgcn_global_load_lds( \
    (const __attribute__((address_space(1))) uint32_t*)(gp), \
    (__attribute__((address_space(3))) uint32_t*)(lp), 16, 0, 0)

#define VMCNT(n) asm volatile("s_waitcnt vmcnt(" #n ")" ::: "memory")
#define CFENCE   asm volatile("" ::: "memory")
#define MFMA16(a,b,c) __builtin_amdgcn_mfma_f32_16x16x32_bf16(a,b,c,0,0,0)
#define MFMAI8(a,b,c) __builtin_amdgcn_mfma_i32_16x16x64_i8(a,b,c,0,0,0)

template<int NXB>
DEV void xcd_remapN(int g, int total, int& x, int& y){
  int xcd = g & 7;
  int k = g >> 3;
  int rows_per_xcd = (total / NXB) >> 3;
  y = xcd * rows_per_xcd + (k / NXB);
  x = k % NXB;
}

DEV void wreduce2(float& a, float& b){
  #pragma unroll
  for (int d = 32; d; d >>= 1){ a += __shfl_xor(a, d); b += __shfl_xor(b, d); }
}

// ---------------- mask compaction ------------------------------------------
__global__ __launch_bounds__(256) void k_compact(const int* __restrict__ mask,
                                                 int* __restrict__ idx, int* __restrict__ cnt){
  int b = blockIdx.x, t = threadIdx.x;
  const int* mb = mask + b*2048;
  int keep[8]; int c = 0;
  #pragma unroll
  for (int u = 0; u < 8; ++u){ keep[u] = (mb[t*8+u] != 0); c += keep[u]; }
  __shared__ int s[256];
  s[t] = c; __syncthreads();
  for (int off = 1; off < 256; off <<= 1){
    int v = (t >= off) ? s[t-off] : 0;
    __syncthreads();
    s[t] += v;
    __syncthreads();
  }
  int pos = s[t] - c;
  #pragma unroll
  for (int u = 0; u < 8; ++u) if (keep[u]) idx[b*2048 + pos++] = t*8 + u;
  if (t == 255) cnt[b] = s[255];
}

// ---------------- gather + rownorm features -> bf16 (wave-per-row) ---------
__global__ __launch_bounds__(256) void k_gather_norm(const float* __restrict__ feat,
        const int* __restrict__ idx, const int* __restrict__ cnt, ushort_t* __restrict__ outp){
  int w = threadIdx.x >> 6, l = threadIdx.x & 63;
  int row = blockIdx.x*4 + w;
  int b = row >> 11, j = row & 2047;
  if (j >= cnt[b]) return;
  int src = idx[b*2048 + j];
  const float* rp = feat + ((size_t)(b*2048 + src))*1024;
  float4 v[4]; float s = 0.f, q = 0.f;
  #pragma unroll
  for (int i = 0; i < 4; ++i){
    v[i] = *(const float4*)(rp + i*256 + l*4);
    s += v[i].x+v[i].y+v[i].z+v[i].w;
    q += v[i].x*v[i].x+v[i].y*v[i].y+v[i].z*v[i].z+v[i].w*v[i].w;
  }
  wreduce2(s, q);
  float mean = s * (1.f/1024.f);
  float rstd = rsqrtf(q*(1.f/1024.f) - mean*mean + 1e-5f);
  ushort_t* op = outp + (size_t)row*1024;
  #pragma unroll
  for (int i = 0; i < 4; ++i){
    ushort4v o;
    o.x = f2bf((v[i].x-mean)*rstd); o.y = f2bf((v[i].y-mean)*rstd);
    o.z = f2bf((v[i].z-mean)*rstd); o.w = f2bf((v[i].w-mean)*rstd);
    *(ushort4v*)(op + i*256 + l*4) = o;
  }
}

// ---------------- rownorm bf16 -> i8 + per-row scale (cnt nullable) --------
__global__ __launch_bounds__(256) void k_rownorm_i8(const ushort_t* __restrict__ in,
        int8_t* __restrict__ outp, float* __restrict__ sca, const int* __restrict__ cnt){
  int w = threadIdx.x >> 6, l = threadIdx.x & 63;
  int row = blockIdx.x*4 + w;
  if (cnt){ int b = row >> 11; if ((row & 2047) >= cnt[b]) return; }
  const ushort_t* rp = in + (size_t)row*1024 + l*16;
  float f[16]; float s = 0.f, q = 0.f;
  #pragma unroll
  for (int i = 0; i < 4; ++i){
    ushort4v u = *(const ushort4v*)(rp + i*4);
    f[i*4+0] = bf2f(u.x); f[i*4+1] = bf2f(u.y);
    f[i*4+2] = bf2f(u.z); f[i*4+3] = bf2f(u.w);
  }
  #pragma unroll
  for (int jj = 0; jj < 16; ++jj){ s += f[jj]; q += f[jj]*f[jj]; }
  wreduce2(s, q);
  float mean = s * (1.f/1024.f);
  float rstd = rsqrtf(q*(1.f/1024.f) - mean*mean + 1e-5f);
  float amax = 0.f;
  #pragma unroll
  for (int jj = 0; jj < 16; ++jj) amax = fmaxf(amax, fabsf(f[jj]-mean));
  #pragma unroll
  for (int d = 32; d; d >>= 1) amax = fmaxf(amax, __shfl_xor(amax, d));
  amax *= rstd;
  float inv = (amax > 0.f) ? 127.f/amax : 0.f;
  if (l == 0) sca[row] = amax * (1.f/127.f);
  uint32_t wds[4];
  #pragma unroll
  for (int i = 0; i < 4; ++i){
    uint32_t wd = 0;
    #pragma unroll
    for (int c = 0; c < 4; ++c){
      int qv = (int)rintf((f[i*4+c]-mean)*rstd*inv);
      wd |= ((uint32_t)(uint8_t)(int8_t)qv) << (c*8);
    }
    wds[i] = wd;
  }
  int4v pk; pk[0]=(int)wds[0]; pk[1]=(int)wds[1]; pk[2]=(int)wds[2]; pk[3]=(int)wds[3];
  *(int4v*)(outp + (size_t)row*1024 + l*16) = pk;
}

// ---------------- rownorm f32 -> i8 + per-row scale ------------------------
__global__ __launch_bounds__(256) void k_rownorm_f32_i8(const float* __restrict__ in,
        int8_t* __restrict__ outp, float* __restrict__ sca){
  int w = threadIdx.x >> 6, l = threadIdx.x & 63;
  int row = blockIdx.x*4 + w;
  const float* rp = in + (size_t)row*1024 + l*16;
  float f[16]; float s = 0.f, q = 0.f;
  #pragma unroll
  for (int i = 0; i < 4; ++i){
    float4 v = *(const float4*)(rp + i*4);
    f[i*4+0] = v.x; f[i*4+1] = v.y; f[i*4+2] = v.z; f[i*4+3] = v.w;
  }
  #pragma unroll
  for (int jj = 0; jj < 16; ++jj){ s += f[jj]; q += f[jj]*f[jj]; }
  wreduce2(s, q);
  float mean = s * (1.f/1024.f);
  float rstd = rsqrtf(q*(1.f/1024.f) - mean*mean + 1e-5f);
  float amax = 0.f;
  #pragma unroll
  for (int jj = 0; jj < 16; ++jj) amax = fmaxf(amax, fabsf(f[jj]-mean));
  #pragma unroll
  for (int d = 32; d; d >>= 1) amax = fmaxf(amax, __shfl_xor(amax, d));
  amax *= rstd;
  float inv = (amax > 0.f) ? 127.f/amax : 0.f;
  if (l == 0) sca[row] = amax * (1.f/127.f);
  uint32_t wds[4];
  #pragma unroll
  for (int i = 0; i < 4; ++i){
    uint32_t wd = 0;
    #pragma unroll
    for (int c = 0; c < 4; ++c){
      int qv = (int)rintf((f[i*4+c]-mean)*rstd*inv);
      wd |= ((uint32_t)(uint8_t)(int8_t)qv) << (c*8);
    }
    wds[i] = wd;
  }
  int4v pk; pk[0]=(int)wds[0]; pk[1]=(int)wds[1]; pk[2]=(int)wds[2]; pk[3]=(int)wds[3];
  *(int4v*)(outp + (size_t)row*1024 + l*16) = pk;
}

// ---------------- bf16 rows -> i8 + per-row scale (no norm) ----------------
template<int PER>
__global__ __launch_bounds__(256) void k_quant_rows(const ushort_t* __restrict__ in,
        int8_t* __restrict__ outp, float* __restrict__ sca){
  const int K = PER*64;
  int w = threadIdx.x >> 6, l = threadIdx.x & 63;
  int row = blockIdx.x*4 + w;
  const ushort_t* rp = in + (size_t)row*K + l*PER;
  float f[PER];
  #pragma unroll
  for (int i = 0; i < PER/4; ++i){
    ushort4v u = *(const ushort4v*)(rp + i*4);
    f[i*4+0] = bf2f(u.x); f[i*4+1] = bf2f(u.y);
    f[i*4+2] = bf2f(u.z); f[i*4+3] = bf2f(u.w);
  }
  float amax = 0.f;
  #pragma unroll
  for (int jj = 0; jj < PER; ++jj) amax = fmaxf(amax, fabsf(f[jj]));
  #pragma unroll
  for (int d = 32; d; d >>= 1) amax = fmaxf(amax, __shfl_xor(amax, d));
  float inv = (amax > 0.f) ? 127.f/amax : 0.f;
  if (l == 0) sca[row] = amax * (1.f/127.f);
  #pragma unroll
  for (int vq = 0; vq < PER/16; ++vq){
    int4v pk;
    #pragma unroll
    for (int i = 0; i < 4; ++i){
      uint32_t wd = 0;
      #pragma unroll
      for (int c = 0; c < 4; ++c){
        int qv = (int)rintf(f[vq*16 + i*4 + c]*inv);
        wd |= ((uint32_t)(uint8_t)(int8_t)qv) << (c*8);
      }
      pk[i] = (int)wd;
    }
    *(int4v*)(outp + (size_t)row*K + l*PER + vq*16) = pk;
  }
}

// ---------------- final layernorm (affine) f32 -> f32 ----------------------
__global__ __launch_bounds__(256) void k_final_ln(const float* __restrict__ x,
        const float* __restrict__ g, const float* __restrict__ bb, float* __restrict__ outp){
  int w = threadIdx.x >> 6, l = threadIdx.x & 63;
  int row = blockIdx.x*4 + w;
  const float* rp = x + (size_t)row*1024;
  float4 v[4]; float s = 0.f, q = 0.f;
  #pragma unroll
  for (int i = 0; i < 4; ++i){
    v[i] = *(const float4*)(rp + i*256 + l*4);
    s += v[i].x+v[i].y+v[i].z+v[i].w;
    q += v[i].x*v[i].x+v[i].y*v[i].y+v[i].z*v[i].z+v[i].w*v[i].w;
  }
  wreduce2(s, q);
  float mean = s * (1.f/1024.f);
  float rstd = rsqrtf(q*(1.f/1024.f) - mean*mean + 1e-5f);
  float* op = outp + (size_t)row*1024;
  #pragma unroll
  for (int i = 0; i < 4; ++i){
    float4 gg = *(const float4*)(g + i*256 + l*4);
    float4 bv = *(const float4*)(bb + i*256 + l*4);
    float4 o;
    o.x = (v[i].x-mean)*rstd*gg.x + bv.x; o.y = (v[i].y-mean)*rstd*gg.y + bv.y;
    o.z = (v[i].z-mean)*rstd*gg.z + bv.z; o.w = (v[i].w-mean)*rstd*gg.w + bv.w;
    *(float4*)(op + i*256 + l*4) = o;
  }
}

// ---------------- x init ----------------------------------------------------
__global__ __launch_bounds__(256) void k_init_x(const float* __restrict__ lat, float* __restrict__ x){
  int v = blockIdx.x*256 + threadIdx.x;
  int row = v >> 8, cv = v & 255;
  ((float4*)x)[v] = ((const float4*)lat)[(row & 63)*256 + cv];
}

// ---------------- batched weight fold + transpose --------------------------
DEV void foldT_body(const float* __restrict__ W, const float* __restrict__ g,
                    float scale, ushort_t* __restrict__ Wt, int K, int N,
                    int n0, int k0){
  __shared__ float Ts[64][65];
  int t = threadIdx.x;
  #pragma unroll
  for (int i = 0; i < 4; ++i){
    int flat = i*1024 + t*4; int r = flat >> 6, c = flat & 63;
    float4 v = *(const float4*)(W + (size_t)(k0+r)*N + n0 + c);
    float gg = (g ? g[k0+r] : 1.f) * scale;
    Ts[r][c] = v.x*gg; Ts[r][c+1] = v.y*gg; Ts[r][c+2] = v.z*gg; Ts[r][c+3] = v.w*gg;
  }
  __syncthreads();
  #pragma unroll
  for (int i = 0; i < 4; ++i){
    int flat = i*1024 + t*4; int rn = flat >> 6, ck = flat & 63;
    ushort4v o;
    o.x = f2bf(Ts[ck][rn]);   o.y = f2bf(Ts[ck+1][rn]);
    o.z = f2bf(Ts[ck+2][rn]); o.w = f2bf(Ts[ck+3][rn]);
    *(ushort4v*)(Wt + (size_t)(n0+rn)*K + k0 + ck) = o;
  }
}

struct FDesc { const float* W; const float* g; ushort_t* dst; float scale; int K; int N; };
#define MAXFD 32
struct FoldTArgs { int cnt; FDesc d[MAXFD]; };

__global__ __launch_bounds__(256) void k_foldT_all(FoldTArgs a){
  const FDesc d = a.d[blockIdx.y];
  int nxb = d.N >> 6;
  int n0 = (blockIdx.x % nxb) * 64;
  int k0 = (blockIdx.x / nxb) * 64;
  if (k0 >= d.K) return;
  foldT_body(d.W, d.g, d.scale, d.dst, d.K, d.N, n0, k0);
}

// ---------------- batched bias fold ----------------------------------------
DEV void foldBias_body(const float* __restrict__ W, const float* __restrict__ bvec,
                       float scale, float* __restrict__ bias, int K, int N, int o0){
  int t = threadIdx.x;
  int ol = t & 31, kc = t >> 5;
  int o = o0 + ol;
  int chunk = K >> 3;
  int c0 = kc*chunk, c1 = c0 + chunk;
  float s0 = 0, s1 = 0, s2 = 0, s3 = 0;
  for (int c = c0; c < c1; c += 4){
    s0 += bvec[c+0]*W[(size_t)(c+0)*N + o];
    s1 += bvec[c+1]*W[(size_t)(c+1)*N + o];
    s2 += bvec[c+2]*W[(size_t)(c+2)*N + o];
    s3 += bvec[c+3]*W[(size_t)(c+3)*N + o];
  }
  __shared__ float red[8][32];
  red[kc][ol] = (s0+s1)+(s2+s3);
  __syncthreads();
  if (kc == 0){
    float tot = 0;
    #pragma unroll
    for (int jj = 0; jj < 8; ++jj) tot += red[jj][ol];
    bias[o] = tot * scale;
  }
}

struct BDesc { const float* W; const float* b; float* dst; float scale; int K; int N; };
#define MAXBD 25
struct BiasArgs { int cnt; BDesc d[MAXBD]; };

__global__ __launch_bounds__(256) void k_foldBias_all(BiasArgs a){
  const BDesc d = a.d[blockIdx.y];
  int o0 = blockIdx.x * 32;
  if (o0 >= d.N) return;
  foldBias_body(d.W, d.b, d.scale, d.dst, d.K, d.N, o0);
}

// ---------------- 64-row i8 GEMM (small shapes, 2+ blocks/CU) --------------
template<int OUTMODE, int BN>
__global__ __launch_bounds__(256, 4) void k_gemm_sm(const int8_t* __restrict__ A,
        const int8_t* __restrict__ Bt, const float* __restrict__ sAr,
        const float* __restrict__ sBr, const float* __restrict__ bias,
        void* __restrict__ Cp, int M, int N, int Kb){
  constexpr int BM = 64;
  constexpr int NIF = BN/32;
  const int n0 = blockIdx.x * BN;
  const int m0 = blockIdx.y * BM;
  __shared__ __align__(16) char sA[2][BM*64];
  __shared__ __align__(16) char sB[2][BN*64];
  const int tid = threadIdx.x;
  const int wave = tid >> 6, lane = tid & 63;
  const int lo = lane & 15, hi = lane >> 4;
  const int wr = wave >> 1, wc = wave & 1;

  auto stage = [&](int buf, int k0){
    {
      int r = tid >> 2;
      int c = (tid & 3) ^ (r & 3);
      const int8_t* gp = A + (size_t)(m0 + r)*Kb + k0 + c*16;
      GLOAD16(gp, &sA[buf][0] + tid*16);
    }
    #pragma unroll
    for (int p = 0; p < BN/64; ++p){
      int r = p*64 + (tid >> 2);
      int c = (tid & 3) ^ (r & 3);
      const int8_t* gp = Bt + (size_t)(n0 + r)*Kb + k0 + c*16;
      GLOAD16(gp, &sB[buf][0] + p*4096 + tid*16);
    }
  };

  int4v acc[2][NIF] = {};
  stage(0, 0);
  const int nk = Kb >> 6;
  for (int ks = 0; ks < nk; ++ks){
    __syncthreads();
    if (ks + 1 < nk) stage((ks+1)&1, (ks+1) << 6);
    const int buf = ks & 1;
    int4v af[2], bfr[NIF];
    #pragma unroll
    for (int mi = 0; mi < 2; ++mi){
      int row = wr*(BM/2) + mi*16 + lo;
      af[mi] = *(const int4v*)(&sA[buf][row*64 + ((hi ^ (row & 3))*16)]);
    }
    #pragma unroll
    for (int ni = 0; ni < NIF; ++ni){
      int row = wc*(BN/2) + ni*16 + lo;
      bfr[ni] = *(const int4v*)(&sB[buf][row*64 + ((hi ^ (row & 3))*16)]);
    }
    #pragma unroll
    for (int mi = 0; mi < 2; ++mi)
      #pragma unroll
      for (int ni = 0; ni < NIF; ++ni)
        acc[mi][ni] = MFMAI8(af[mi], bfr[ni], acc[mi][ni]);
  }
  #pragma unroll
  for (int ni = 0; ni < NIF; ++ni){
    int col = n0 + wc*(BN/2) + ni*16 + lo;
    float bv = bias ? bias[col] : 0.f;
    float sb = sBr[col];
    #pragma unroll
    for (int mi = 0; mi < 2; ++mi){
      int rbase = m0 + wr*(BM/2) + mi*16 + hi*4;
      #pragma unroll
      for (int rr = 0; rr < 4; ++rr){
        int row = rbase + rr;
        float v = (float)acc[mi][ni][rr] * (sAr[row]*sb) + bv;
        size_t off = (size_t)row*N + col;
        if (OUTMODE == 0)      ((ushort_t*)Cp)[off] = f2bf(v);
        else if (OUTMODE == 1) ((ushort_t*)Cp)[off] = f2bf(fmaxf(v, 0.f));
        else                   ((float*)Cp)[off] += v;
      }
    }
  }
}

// ---------------- 256x256 8-phase bf16 GEMM (down-proj) --------------------
template<bool SKIP, int NXB>
__global__ __launch_bounds__(512, 2) void k_gemm256p8(const ushort_t* __restrict__ A,
        const ushort_t* __restrict__ Bt, const float* __restrict__ bias,
        ushort_t* __restrict__ Cp, int M, int N, int K, const int* __restrict__ cnt){
  int bx, by;
  xcd_remapN<NXB>(blockIdx.x, gridDim.x, bx, by);
  const int n0 = bx * 256;
  const int m0 = by * 256;
  if (SKIP){ int b = m0 >> 11; if ((m0 & 2047) >= cnt[b]) return; }
  __shared__ __align__(16) ushort_t sA[2][256*64];
  __shared__ __align__(16) ushort_t sB[2][256*64];
  const int tid = threadIdx.x;
  const int wave = tid >> 6, lane = tid & 63;
  const int lo = lane & 15, hi = lane >> 4;
  const int wm = wave >> 2, wn = wave & 3;
  const int srow = lane >> 3;
  const int schunk = (lane & 7) ^ srow;
  auto stageHalf = [&](ushort_t* dst, const ushort_t* __restrict__ G, int grow0,
                       int half, int k0){
    #pragma unroll
    for (int p = 0; p < 2; ++p){
      int rbase = half*128 + p*64 + wave*8;
      const ushort_t* gp = G + (size_t)(grow0 + rbase + srow)*K + k0 + schunk*8;
      char* lp = (char*)dst + (size_t)rbase*128;
      GLOAD16(gp, lp);
    }
  };
  auto ldsA = [&](int buf, int row, int kk)->short8{
    int ch = ((kk<<2) + hi) ^ (row & 7);
    return *(const short8*)((const char*)sA + (size_t)buf*32768 + (size_t)row*128 + ch*16);
  };
  auto ldsB = [&](int buf, int row, int kk)->short8{
    int ch = ((kk<<2) + hi) ^ (row & 7);
    return *(const short8*)((const char*)sB + (size_t)buf*32768 + (size_t)row*128 + ch*16);
  };
  f32x4 acc[8][4] = {};

  short8 af[4][2], bg[2][2];
#define LOADA(BUF, AH) \
    _Pragma("unroll") for (int mi_ = 0; mi_ < 4; ++mi_) \
      _Pragma("unroll") for (int kk_ = 0; kk_ < 2; ++kk_) \
        af[mi_][kk_] = ldsA(BUF, (AH)*128 + wm*64 + mi_*16 + lo, kk_);
#define LOADB(BUF, BH) \
    _Pragma("unroll") for (int nj_ = 0; nj_ < 2; ++nj_) \
      _Pragma("unroll") for (int kk_ = 0; kk_ < 2; ++kk_) \
        bg[nj_][kk_] = ldsB(BUF, (BH)*128 + wn*32 + nj_*16 + lo, kk_);
#define MMQ(AH, BH) \
    __builtin_amdgcn_s_barrier(); CFENCE; \
    __builtin_amdgcn_s_setprio(1); \
    _Pragma("unroll") for (int mi_ = 0; mi_ < 4; ++mi_) \
      _Pragma("unroll") for (int nj_ = 0; nj_ < 2; ++nj_) \
        _Pragma("unroll") for (int kk_ = 0; kk_ < 2; ++kk_) \
          acc[(AH)*4+mi_][(BH)*2+nj_] = \
            MFMA16(af[mi_][kk_], bg[nj_][kk_], acc[(AH)*4+mi_][(BH)*2+nj_]); \
    __builtin_amdgcn_s_setprio(0); CFENCE; \
    __builtin_amdgcn_s_barrier(); CFENCE;

  stageHalf(&sA[0][0], A,  m0, 0, 0);
  stageHalf(&sB[0][0], Bt, n0, 0, 0);
  stageHalf(&sA[0][0], A,  m0, 1, 0);
  stageHalf(&sB[0][0], Bt, n0, 1, 0);
  stageHalf(&sA[1][0], A,  m0, 0, 64);
  stageHalf(&sB[1][0], Bt, n0, 1, 64);
  VMCNT(4);
  __builtin_amdgcn_s_barrier();
  CFENCE;

  const int NI = K >> 7;
  for (int i = 0; i < NI; ++i){
    const int kt = i << 7;
    const bool lastI = (i == NI-1);
    LOADA(0,0) LOADB(0,0)
    stageHalf(&sA[1][0], A,  m0, 1, kt+64);
    MMQ(0,0)
    LOADB(0,1)
    stageHalf(&sB[1][0], Bt, n0, 0, kt+64);
    MMQ(0,1)
    LOADA(0,1)
    if (!lastI) stageHalf(&sA[0][0], A,  m0, 0, kt+128);
    MMQ(1,1)
    LOADB(0,0)
    if (!lastI) stageHalf(&sB[0][0], Bt, n0, 1, kt+128);
    if (lastI){ VMCNT(0); } else { VMCNT(4); }
    MMQ(1,0)
    LOADA(1,0) LOADB(1,0)
    if (!lastI) stageHalf(&sA[0][0], A,  m0, 1, kt+128);
    MMQ(0,0)
    LOADB(1,1)
    if (!lastI) stageHalf(&sB[0][0], Bt, n0, 0, kt+128);
    MMQ(0,1)
    LOADA(1,1)
    if (!lastI) stageHalf(&sA[1][0], A,  m0, 0, kt+192);
    MMQ(1,1)
    LOADB(1,0)
    if (!lastI){ stageHalf(&sB[1][0], Bt, n0, 1, kt+192); VMCNT(4); }
    MMQ(1,0)
  }
#undef LOADA
#undef LOADB
#undef MMQ

  #pragma unroll
  for (int b2 = 0; b2 < 2; ++b2)
    #pragma unroll
    for (int nj = 0; nj < 2; ++nj){
      int col = n0 + b2*128 + wn*32 + nj*16 + lo;
      float bv = bias ? bias[col] : 0.f;
      #pragma unroll
      for (int a2 = 0; a2 < 2; ++a2)
        #pragma unroll
        for (int mi4 = 0; mi4 < 4; ++mi4){
          int rbase = m0 + a2*128 + wm*64 + mi4*16 + hi*4;
          #pragma unroll
          for (int rr = 0; rr < 4; ++rr){
            float v = acc[a2*4+mi4][b2*2+nj][rr] + bv;
            Cp[(size_t)(rbase + rr)*N + col] = f2bf(v);
          }
        }
    }
}

// ---------------- 256x256 8-phase i8 GEMM (KV projections) -----------------
template<bool SKIP, int NXB>
__global__ __launch_bounds__(512, 2) void k_gemm256i8(const int8_t* __restrict__ A,
        const int8_t* __restrict__ Bt, const float* __restrict__ sAr,
        const float* __restrict__ sBr, const float* __restrict__ bias,
        ushort_t* __restrict__ Cp, int M, int N, int Kb, const int* __restrict__ cnt){
  int bx, by;
  xcd_remapN<NXB>(blockIdx.x, gridDim.x, bx, by);
  const int n0 = bx * 256;
  const int m0 = by * 256;
  if (SKIP){ int b = m0 >> 11; if ((m0 & 2047) >= cnt[b]) return; }
  __shared__ __align__(16) char sAl[2][256*128];
  __shared__ __align__(16) char sBl[2][256*128];
  const int tid = threadIdx.x;
  const int wave = tid >> 6, lane = tid & 63;
  const int lo = lane & 15, hi = lane >> 4;
  const int wm = wave >> 2, wn = wave & 3;
  const int srow = lane >> 3;
  const int schunk = (lane & 7) ^ srow;
  auto stageHalf = [&](char* dst, const int8_t* __restrict__ G, int grow0,
                       int half, int k0){            // k0 in BYTES
    #pragma unroll
    for (int p = 0; p < 2; ++p){
      int rbase = half*128 + p*64 + wave*8;
      const int8_t* gp = G + (size_t)(grow0 + rbase + srow)*Kb + k0 + schunk*16;
      char* lp = dst + (size_t)rbase*128;
      GLOAD16(gp, lp);
    }
  };
  auto ldsA = [&](int buf, int row, int kk)->int4v{
    int ch = ((kk<<2) + hi) ^ (row & 7);
    return *(const int4v*)((const char*)sAl + (size_t)buf*32768 + (size_t)row*128 + ch*16);
  };
  auto ldsB = [&](int buf, int row, int kk)->int4v{
    int ch = ((kk<<2) + hi) ^ (row & 7);
    return *(const int4v*)((const char*)sBl + (size_t)buf*32768 + (size_t)row*128 + ch*16);
  };
  int4v acc[8][4] = {};

  int4v af[4][2], bg[2][2];
#define LOADA(BUF, AH) \
    _Pragma("unroll") for (int mi_ = 0; mi_ < 4; ++mi_) \
      _Pragma("unroll") for (int kk_ = 0; kk_ < 2; ++kk_) \
        af[mi_][kk_] = ldsA(BUF, (AH)*128 + wm*64 + mi_*16 + lo, kk_);
#define LOADB(BUF, BH) \
    _Pragma("unroll") for (int nj_ = 0; nj_ < 2; ++nj_) \
      _Pragma("unroll") for (int kk_ = 0; kk_ < 2; ++kk_) \
        bg[nj_][kk_] = ldsB(BUF, (BH)*128 + wn*32 + nj_*16 + lo, kk_);
#define MMQ(AH, BH) \
    __builtin_amdgcn_s_barrier(); CFENCE; \
    __builtin_amdgcn_s_setprio(1); \
    _Pragma("unroll") for (int mi_ = 0; mi_ < 4; ++mi_) \
      _Pragma("unroll") for (int nj_ = 0; nj_ < 2; ++nj_) \
        _Pragma("unroll") for (int kk_ = 0; kk_ < 2; ++kk_) \
          acc[(AH)*4+mi_][(BH)*2+nj_] = \
            MFMAI8(af[mi_][kk_], bg[nj_][kk_], acc[(AH)*4+mi_][(BH)*2+nj_]); \
    __builtin_amdgcn_s_setprio(0); CFENCE; \
    __builtin_amdgcn_s_barrier(); CFENCE;

  stageHalf(&sAl[0][0], A,  m0, 0, 0);
  stageHalf(&sBl[0][0], Bt, n0, 0, 0);
  stageHalf(&sAl[0][0], A,  m0, 1, 0);
  stageHalf(&sBl[0][0], Bt, n0, 1, 0);
  stageHalf(&sAl[1][0], A,  m0, 0, 128);
  stageHalf(&sBl[1][0], Bt, n0, 1, 128);
  VMCNT(4);
  __builtin_amdgcn_s_barrier();
  CFENCE;

  const int NI = Kb >> 8;
  for (int i = 0; i < NI; ++i){
    const int kt = i << 8;
    const bool lastI = (i == NI-1);
    LOADA(0,0) LOADB(0,0)
    stageHalf(&sAl[1][0], A,  m0, 1, kt+128);
    MMQ(0,0)
    LOADB(0,1)
    stageHalf(&sBl[1][0], Bt, n0, 0, kt+128);
    MMQ(0,1)
    LOADA(0,1)
    if (!lastI) stageHalf(&sAl[0][0], A,  m0, 0, kt+256);
    MMQ(1,1)
    LOADB(0,0)
    if (!lastI) stageHalf(&sBl[0][0], Bt, n0, 1, kt+256);
    if (lastI){ VMCNT(0); } else { VMCNT(4); }
    MMQ(1,0)
    LOADA(1,0) LOADB(1,0)
    if (!lastI) stageHalf(&sAl[0][0], A,  m0, 1, kt+256);
    MMQ(0,0)
    LOADB(1,1)
    if (!lastI) stageHalf(&sBl[0][0], Bt, n0, 0, kt+256);
    MMQ(0,1)
    LOADA(1,1)
    if (!lastI) stageHalf(&sAl[1][0], A,  m0, 0, kt+384);
    MMQ(1,1)
    LOADB(1,0)
    if (!lastI){ stageHalf(&sBl[1][0], Bt, n0, 1, kt+384); VMCNT(4); }
    MMQ(1,0)
  }
#undef LOADA
#undef LOADB
#undef MMQ

  #pragma unroll
  for (int b2 = 0; b2 < 2; ++b2)
    #pragma unroll
    for (int nj = 0; nj < 2; ++nj){
      int col = n0 + b2*128 + wn*32 + nj*16 + lo;
      float bv = bias ? bias[col] : 0.f;
      float sb = sBr[col];
      #pragma unroll
      for (int a2 = 0; a2 < 2; ++a2)
        #pragma unroll
        for (int mi4 = 0; mi4 < 4; ++mi4){
          int rbase = m0 + a2*128 + wm*64 + mi4*16 + hi*4;
          #pragma unroll
          for (int rr = 0; rr < 4; ++rr){
            int row = rbase + rr;
            float v = (float)acc[a2*4+mi4][b2*2+nj][rr] * (sAr[row]*sb) + bv;
            Cp[(size_t)row*N + col] = f2bf(v);
          }
        }
    }
}

// ---------------- flash attention (pipelined): one block per (b,h) ---------
__global__ __launch_bounds__(256) void k_attn(const ushort_t* __restrict__ qb,
        const ushort_t* __restrict__ kvb, int kstride, const int* __restrict__ cnt,
        ushort_t* __restrict__ outb){
  const int bh = blockIdx.x;
  const int b = bh >> 4, h = bh & 15;
  const int t = threadIdx.x;
  const int wave = t >> 6, lane = t & 63, lo = lane & 15, hi = lane >> 4;
  __shared__ ushort_t Qs[64*64];
  __shared__ ushort_t Ks[2][64*64];
  __shared__ ushort_t Vt[2][64][72];
  __shared__ ushort_t Ps[4][16][72];

  const int count = cnt[b];

  #pragma unroll
  for (int p = 0; p < 2; ++p){
    int r = p*32 + wave*8 + (lane >> 3);
    int c = (lane & 7) ^ (r & 7);
    const ushort_t* gp = qb + (size_t)(b*64 + r)*1024 + h*64 + c*8;
    char* lp = (char*)Qs + p*4096 + wave*1024;
    GLOAD16(gp, lp);
  }

  auto stageK = [&](int buf, int tt){
    #pragma unroll
    for (int p = 0; p < 2; ++p){
      int r = p*32 + wave*8 + (lane >> 3);
      int c = (lane & 7) ^ (r & 7);
      const ushort_t* gp = kvb + (size_t)(b*2048 + tt*64 + r)*kstride + h*64 + c*8;
      char* lp = (char*)(&Ks[buf][0]) + p*4096 + wave*1024;
      GLOAD16(gp, lp);
    }
  };
  const int vjj = (t & 31)*2, vc = (t >> 5)*8;
  ushort4v va0, va1, vb0, vb1;
  auto issueV = [&](int tt){
    const ushort_t* g0 = kvb + (size_t)(b*2048 + tt*64 + vjj)*kstride + 1024 + h*64 + vc;
    va0 = *(const ushort4v*)(g0);
    va1 = *(const ushort4v*)(g0 + 4);
    vb0 = *(const ushort4v*)(g0 + kstride);
    vb1 = *(const ushort4v*)(g0 + kstride + 4);
  };
  auto writeV = [&](int buf, int tt){
    bool va  = (tt*64 + vjj)     < count;
    bool vb2 = (tt*64 + vjj + 1) < count;
    #pragma unroll
    for (int u = 0; u < 8; ++u){
      ushort_t ea = (u < 4) ? ((ushort_t*)&va0)[u] : ((ushort_t*)&va1)[u-4];
      ushort_t eb = (u < 4) ? ((ushort_t*)&vb0)[u] : ((ushort_t*)&vb1)[u-4];
      uint32_t word = (va ? (uint32_t)ea : 0u) | ((vb2 ? (uint32_t)eb : 0u) << 16);
      *(uint32_t*)(&Vt[buf][vc+u][vjj]) = word;
    }
  };

  f32x4 oacc[4] = {};
  float m[4], l[4];
  #pragma unroll
  for (int rr = 0; rr < 4; ++rr){ m[rr] = -__builtin_inff(); l[rr] = 0.f; }

  const int ntiles = (count + 63) >> 6;
  if (ntiles > 0){ stageK(0, 0); issueV(0); }

  for (int tt = 0; tt < ntiles; ++tt){
    const int buf = tt & 1;
    writeV(buf, tt);
    if (tt + 1 < ntiles){ stageK(buf^1, tt+1); issueV(tt+1); }
    asm volatile("s_waitcnt lgkmcnt(0)" ::: "memory");
    __builtin_amdgcn_s_barrier();
    CFENCE;

    f32x4 s[4] = {};
    #pragma unroll
    for (int kk = 0; kk < 2; ++kk){
      int rA = wave*16 + lo;
      short8 aq = *(const short8*)(&Qs[rA*64 + (((kk*4 + hi) ^ (rA & 7))*8)]);
      #pragma unroll
      for (int ni = 0; ni < 4; ++ni){
        int rB = ni*16 + lo;
        short8 bk = *(const short8*)(&Ks[buf][rB*64 + (((kk*4 + hi) ^ (rB & 7))*8)]);
        s[ni] = MFMA16(aq, bk, s[ni]);
      }
    }
    #pragma unroll
    for (int ni = 0; ni < 4; ++ni){
      if (tt*64 + ni*16 + lo >= count){
        s[ni][0] = s[ni][1] = s[ni][2] = s[ni][3] = -__builtin_inff();
      }
    }
    float p[4][4];
    #pragma unroll
    for (int rr = 0; rr < 4; ++rr){
      float mx = fmaxf(fmaxf(s[0][rr], s[1][rr]), fmaxf(s[2][rr], s[3][rr]));
      #pragma unroll
      for (int d = 1; d < 16; d <<= 1) mx = fmaxf(mx, __shfl_xor(mx, d));
      float mnew = fmaxf(m[rr], mx);
      float sc = __expf(m[rr] - mnew);
      float rsum = 0.f;
      #pragma unroll
      for (int ni = 0; ni < 4; ++ni){
        float pv = __expf(s[ni][rr] - mnew);
        p[ni][rr] = pv;
        rsum += pv;
      }
      #pragma unroll
      for (int d = 1; d < 16; d <<= 1) rsum += __shfl_xor(rsum, d);
      l[rr] = l[rr]*sc + rsum;
      m[rr] = mnew;
      #pragma unroll
      for (int ni = 0; ni < 4; ++ni) oacc[ni][rr] *= sc;
    }
    #pragma unroll
    for (int ni = 0; ni < 4; ++ni)
      #pragma unroll
      for (int rr = 0; rr < 4; ++rr)
        Ps[wave][hi*4+rr][ni*16+lo] = f2bf(p[ni][rr]);
    asm volatile("s_waitcnt lgkmcnt(0)" ::: "memory");
    #pragma unroll
    for (int kk = 0; kk < 2; ++kk){
      short8 pa = *(const short8*)(&Ps[wave][lo][kk*32 + hi*8]);
      #pragma unroll
      for (int ni = 0; ni < 4; ++ni){
        short8 bv = *(const short8*)(&Vt[buf][ni*16 + lo][kk*32 + hi*8]);
        oacc[ni] = MFMA16(pa, bv, oacc[ni]);
      }
    }
    CFENCE;
    __builtin_amdgcn_s_barrier();
    CFENCE;
  }
  #pragma unroll
  for (int rr = 0; rr < 4; ++rr){
    float inv = (l[rr] > 0.f) ? 1.f/l[rr] : 0.f;
    #pragma unroll
    for (int ni = 0; ni < 4; ++ni){
      size_t off = (size_t)(b*64 + wave*16 + hi*4 + rr)*1024 + h*64 + ni*16 + lo;
      outb[off] = f2bf(oacc[ni][rr] * inv);
    }
  }
}

// ---------------------------------------------------------------------------
extern "C" void kernel_launch(void* const* d_in, const int* in_sizes, int n_in,
                              void* d_out, int out_size, void* d_ws, size_t ws_size,
                              hipStream_t stream){
  const float* features = (const float*)d_in[0];
  const int*   mask     = (const int*)  d_in[1];
  const float* latents  = (const float*)d_in[2];
  const float* W_down   = (const float*)d_in[3];
  const float* nin_g    = (const float*)d_in[4];
  const float* nin_b    = (const float*)d_in[5];
  const float* lf_g     = (const float*)d_in[6];
  const float* lf_b     = (const float*)d_in[7];
  const float* ll_g     = (const float*)d_in[8];
  const float* ll_b     = (const float*)d_in[9];
  const float* Wq       = (const float*)d_in[10];
  const float* Wk       = (const float*)d_in[11];
  const float* Wv       = (const float*)d_in[12];
  const float* ffln_g   = (const float*)d_in[13];
  const float* ffln_b   = (const float*)d_in[14];
  const float* ff_w1    = (const float*)d_in[15];
  const float* ff_w2    = (const float*)d_in[16];
  const float* nout_g   = (const float*)d_in[17];
  const float* nout_b   = (const float*)d_in[18];

  char* ws = (char*)d_ws;
  size_t off = 0;
  auto alloc = [&](size_t bytes)->char*{
    char* p = ws + off;
    off += (bytes + 255) & ~(size_t)255;
    return p;
  };
  const size_t SZW = (size_t)1024*1024*2;       // 2 MB (1024x1024 bf16)

  ushort_t* FHAT  = (ushort_t*)alloc((size_t)65536*1024*2);   // down-proj out
  int8_t*   I8A   = (int8_t*)  alloc((size_t)65536*1024);     // LN'd fhat, i8
  float*    SA    = (float*)   alloc((size_t)65536*4);
  int8_t*   I8KV  = (int8_t*)  alloc((size_t)12288*1024);     // KV weights i8
  float*    SKV   = (float*)   alloc((size_t)12288*4);
  int8_t*   I8Q   = (int8_t*)  alloc((size_t)6144*1024);      // Q weights i8
  float*    SQW   = (float*)   alloc((size_t)6144*4);
  int8_t*   I8W1  = (int8_t*)  alloc((size_t)12288*1024);     // FF1 weights i8
  float*    SW1   = (float*)   alloc((size_t)12288*4);
  int8_t*   I8W2  = (int8_t*)  alloc((size_t)6144*2048);      // FF2 weights i8
  float*    SW2   = (float*)   alloc((size_t)6144*4);
  ushort_t* WDT   = (ushort_t*)alloc(SZW);
  ushort_t* WQT6  = (ushort_t*)alloc(SZW*6);
  ushort_t* WKVT6 = (ushort_t*)alloc(SZW*2*6);
  ushort_t* W1T6  = (ushort_t*)alloc(SZW*2*6);
  ushort_t* W2T6  = (ushort_t*)alloc(SZW*2*6);
  float* BD   = (float*)alloc(1024*4);
  float* BQ6  = (float*)alloc(1024*4*6);
  float* BKV6 = (float*)alloc(2048*4*6);
  float* B16  = (float*)alloc(2048*4*6);
  float*    X    = (float*)   alloc((size_t)2048*1024*4);
  int8_t*   I8X  = (int8_t*)  alloc((size_t)2048*1024);
  float*    SX   = (float*)   alloc((size_t)2048*4);
  ushort_t* QP   = (ushort_t*)alloc((size_t)2048*1024*2);
  ushort_t* OUTB = (ushort_t*)alloc((size_t)2048*1024*2);
  int8_t*   I8O  = (int8_t*)  alloc((size_t)2048*1024);
  float*    SO   = (float*)   alloc((size_t)2048*4);
  ushort_t* H1   = (ushort_t*)alloc((size_t)2048*2048*2);
  int8_t*   I8H  = (int8_t*)  alloc((size_t)2048*2048);
  float*    SH   = (float*)   alloc((size_t)2048*4);
  int* CNT = (int*)alloc(32*4);
  int* IDX = (int*)alloc((size_t)65536*4);
  ushort_t* KVBUF = (ushort_t*)alloc((size_t)65536*2048*2);   // 256 MB
  ushort_t* FNORM = KVBUF;   // transient alias (dead before KV GEMM writes)
  (void)in_sizes; (void)n_in; (void)out_size; (void)ws_size;

  const float scale = 0.125f;  // DH^-0.5

  // ---- batched weight folds (all depth-independent) ----
  FoldTArgs fa; int nf = 0;
  auto addF = [&](const float* W, const float* g, float sc, ushort_t* dst, int K, int N){
    fa.d[nf++] = FDesc{W, g, dst, sc, K, N};
  };
  addF(W_down, nin_g, 1.f, WDT, 1024, 1024);
  for (int i = 0; i < 6; ++i){
    const float* Wqi = Wq + (size_t)i*1024*1024;
    const float* Wki = Wk + (size_t)i*1024*1024;
    const float* Wvi = Wv + (size_t)i*1024*1024;
    const float* W1i = ff_w1 + (size_t)i*1024*2048;
    const float* W2i = ff_w2 + (size_t)i*2048*1024;
    addF(Wqi, ll_g + i*1024, scale, WQT6  + i*(SZW/2),        1024, 1024);
    addF(Wki, lf_g + i*1024, 1.f,   WKVT6 + i*SZW,            1024, 1024);
    addF(Wvi, lf_g + i*1024, 1.f,   WKVT6 + i*SZW + (SZW/2),  1024, 1024);
    addF(W1i, ffln_g + i*1024, 1.f, W1T6  + i*SZW,            1024, 2048);
    addF(W2i, nullptr, 1.f,         W2T6  + i*SZW,            2048, 1024);
  }
  fa.cnt = nf;

  BiasArgs ba; int nb = 0;
  auto addB = [&](const float* W, const float* b, float sc, float* dst, int K, int N){
    ba.d[nb++] = BDesc{W, b, dst, sc, K, N};
  };
  addB(W_down, nin_b, 1.f, BD, 1024, 1024);
  for (int i = 0; i < 6; ++i){
    const float* Wqi = Wq + (size_t)i*1024*1024;
    const float* Wki = Wk + (size_t)i*1024*1024;
    const float* Wvi = Wv + (size_t)i*1024*1024;
    const float* W1i = ff_w1 + (size_t)i*1024*2048;
    addB(Wqi, ll_b + i*1024, scale, BQ6  + i*1024,        1024, 1024);
    addB(Wki, lf_b + i*1024, 1.f,   BKV6 + i*2048,        1024, 1024);
    addB(Wvi, lf_b + i*1024, 1.f,   BKV6 + i*2048 + 1024, 1024, 1024);
    addB(W1i, ffln_b + i*1024, 1.f, B16  + i*2048,        1024, 2048);
  }
  ba.cnt = nb;

  // ---- setup ----
  k_compact     <<<32,    256, 0, stream>>>(mask, IDX, CNT);
  k_gather_norm <<<16384, 256, 0, stream>>>(features, IDX, CNT, FNORM);
  k_foldT_all   <<<dim3(512, nf), 256, 0, stream>>>(fa);
  k_foldBias_all<<<dim3(64,  nb), 256, 0, stream>>>(ba);
  k_quant_rows<16><<<3072, 256, 0, stream>>>(WKVT6, I8KV, SKV);  // 12288 rows K=1024
  k_quant_rows<16><<<1536, 256, 0, stream>>>(WQT6,  I8Q,  SQW);  //  6144 rows K=1024
  k_quant_rows<16><<<3072, 256, 0, stream>>>(W1T6,  I8W1, SW1);  // 12288 rows K=1024
  k_quant_rows<32><<<1536, 256, 0, stream>>>(W2T6,  I8W2, SW2);  //  6144 rows K=2048
  k_gemm256p8<true,4><<<1024, 512, 0, stream>>>(FNORM, WDT, BD, FHAT, 65536, 1024, 1024, CNT);
  k_rownorm_i8  <<<16384, 256, 0, stream>>>(FHAT, I8A, SA, CNT);
  k_init_x      <<<2048,  256, 0, stream>>>(latents, X);

  for (int i = 0; i < 6; ++i){
    k_gemm256i8<true,8><<<2048, 512, 0, stream>>>(I8A, I8KV + (size_t)i*2048*1024,
                                                  SA, SKV + i*2048, BKV6 + i*2048,
                                                  KVBUF, 65536, 2048, 1024, CNT);
    k_rownorm_f32_i8<<<512, 256, 0, stream>>>(X, I8X, SX);
    k_gemm_sm<0,64><<<dim3(16,32), 256, 0, stream>>>(I8X, I8Q + (size_t)i*1024*1024,
                                                     SX, SQW + i*1024, BQ6 + i*1024,
                                                     QP, 2048, 1024, 1024);
    k_attn<<<512, 256, 0, stream>>>(QP, KVBUF, 2048, CNT, OUTB);
    k_rownorm_i8<<<512, 256, 0, stream>>>(OUTB, I8O, SO, nullptr);
    k_gemm_sm<1,128><<<dim3(16,32), 256, 0, stream>>>(I8O, I8W1 + (size_t)i*2048*1024,
                                                      SO, SW1 + i*2048, B16 + i*2048,
                                                      H1, 2048, 2048, 1024);
    k_quant_rows<32><<<512, 256, 0, stream>>>(H1, I8H, SH);
    k_gemm_sm<2,64><<<dim3(16,32), 256, 0, stream>>>(I8H, I8W2 + (size_t)i*1024*2048,
                                                     SH, SW2 + i*1024, nullptr,
                                                     X, 2048, 1024, 2048);
  }
  k_final_ln<<<512, 256, 0, stream>>>(X, nout_g, nout_b, (float*)d_out);
}